// Round 6
// baseline (186.616 us; speedup 1.0000x reference)
//
#include <hip/hip_runtime.h>
#include <math.h>

#define N_IMG 12
#define C_IN 64
#define HFEAT 28
#define WFEAT 50
#define P_PIX 1400
#define ND 32
#define CB 128
#define BH 128
#define BW 128
#define BEPS 1e-5f

typedef float f32x4 __attribute__((ext_vector_type(4)));
typedef __bf16 bf16x8 __attribute__((ext_vector_type(8)));

__device__ __forceinline__ float gelu_exact(float x) {
  return 0.5f * x * (1.0f + erff(x * 0.70710678118654752440f));
}

// ---------------- all weight preps fused: fp32 [co][ci][3][3] -> bf16 [tap][co][ci]
__global__ __launch_bounds__(256) void k_wprep_all(
    const float* __restrict__ dh_w1, const float* __restrict__ br_w1,
    const float* __restrict__ br_w2, __bf16* __restrict__ w1dh,
    __bf16* __restrict__ w1bev, __bf16* __restrict__ w2bev) {
  int idx = blockIdx.x * 256 + threadIdx.x;
  if (idx < 9 * 64 * 64) {
    int ci = idx & 63, co = (idx >> 6) & 63, tap = idx >> 12;
    w1dh[idx] = (__bf16)dh_w1[(co * 64 + ci) * 9 + tap];
  } else if (idx < 9 * 64 * 64 + 9 * CB * CB) {
    int k = idx - 9 * 64 * 64;
    int ci = k % CB, co = (k / CB) % CB, tap = k / (CB * CB);
    w1bev[k] = (__bf16)br_w1[((size_t)co * CB + ci) * 9 + tap];
  } else if (idx < 9 * 64 * 64 + 2 * 9 * CB * CB) {
    int k = idx - 9 * 64 * 64 - 9 * CB * CB;
    int ci = k % CB, co = (k / CB) % CB, tap = k / (CB * CB);
    w2bev[k] = (__bf16)br_w2[((size_t)co * CB + ci) * 9 + tap];
  }
}

// ---------------- feat NCHW fp32 -> NHWC bf16 [n][p][64] ----------------
__global__ __launch_bounds__(256) void k_transpose(const float* __restrict__ feat,
                                                   __bf16* __restrict__ featT) {
  __shared__ float t[64][65];
  const int n = blockIdx.x / 22;
  const int p0 = (blockIdx.x % 22) * 64;
  const float* fb = feat + (size_t)n * C_IN * P_PIX;
  const int lane = threadIdx.x & 63;
  const int grp = threadIdx.x >> 6;
#pragma unroll
  for (int j = 0; j < 16; ++j) {
    int ci = j * 4 + grp;
    int px = p0 + lane;
    t[ci][lane] = (px < P_PIX) ? fb[ci * P_PIX + px] : 0.f;
  }
  __syncthreads();
#pragma unroll
  for (int k = 0; k < 2; ++k) {
    int gid = threadIdx.x * 2 + k;
    int pxl = gid >> 3, g = gid & 7;
    int px = p0 + pxl;
    if (px < P_PIX) {
      __bf16 tmp[8];
#pragma unroll
      for (int j = 0; j < 8; ++j) tmp[j] = (__bf16)t[g * 8 + j][pxl];
      *(bf16x8*)(featT + ((size_t)n * P_PIX + px) * C_IN + g * 8) = *(bf16x8*)tmp;
    }
  }
}

// ---------------- depth-head 3x3 conv via MFMA, one block per (image,row) ----
// LDS: A [0,19968) = 3 rows x 52 x 64ci bf16 swizzled; W dbuf [19968, +2*8192)
#define DA 0
#define DW 19968

__global__ __launch_bounds__(256) void k_dh(
    const __bf16* __restrict__ featT, const __bf16* __restrict__ w1bf,
    const float* __restrict__ dh_b1, const float* __restrict__ dh_g,
    const float* __restrict__ dh_be, const float* __restrict__ dh_m,
    const float* __restrict__ dh_v, __bf16* __restrict__ hbuf) {
  __shared__ __align__(16) unsigned char lds[19968 + 2 * 8192];
  const int n = blockIdx.x / HFEAT;
  const int r = blockIdx.x % HFEAT;
  const int tid = threadIdx.x;
  const int l = tid & 63;
  const int wid = tid >> 6;
  const int lrow = l & 15;
  const int kgrp = l >> 4;

  // ---- stage A: rows r-1..r+1, xcols -1..50, 64 ci ----
  {
    const __bf16* fT = featT + (size_t)n * P_PIX * C_IN;
    for (int i = tid; i < 1248; i += 256) {
      int q = i >> 3, g = i & 7;
      int hrow = q / 52, hx = q % 52;
      int gy = r - 1 + hrow, gx = hx - 1;
      bf16x8 val;
      if (gy >= 0 && gy < HFEAT && gx >= 0 && gx < WFEAT) {
        val = *(const bf16x8*)(fT + ((size_t)(gy * WFEAT + gx)) * C_IN + g * 8);
      } else {
        __bf16 z[8] = {};
        val = *(bf16x8*)z;
      }
      *(bf16x8*)(lds + DA + q * 128 + ((g ^ (q & 7)) << 4)) = val;
    }
  }
  // ---- stage W tap 0 into buf 0 ----
  for (int i = tid; i < 512; i += 256) {
    int co = i >> 3, g = i & 7;
    uint4 val = *(const uint4*)(w1bf + co * 64 + g * 8);
    *(uint4*)(lds + DW + co * 128 + ((g ^ (co & 7)) << 4)) = val;
  }
  __syncthreads();

  const int px_local = wid * 16 + lrow;          // A-frag row (0..63)
  const int xread = px_local < 50 ? px_local : 49;  // clamp pad lanes in-bounds

  f32x4 acc[4];
#pragma unroll
  for (int j = 0; j < 4; ++j) acc[j] = {0.f, 0.f, 0.f, 0.f};

  for (int tap = 0; tap < 9; ++tap) {
    // prefetch next tap's weights into the other buffer
    if (tap < 8) {
      const __bf16* wp = w1bf + (size_t)(tap + 1) * 4096;
      unsigned char* wb = lds + DW + ((tap + 1) & 1) * 8192;
      for (int i = tid; i < 512; i += 256) {
        int co = i >> 3, g = i & 7;
        uint4 val = *(const uint4*)(wp + co * 64 + g * 8);
        *(uint4*)(wb + co * 128 + ((g ^ (co & 7)) << 4)) = val;
      }
    }
    const int ky = tap / 3, kx = tap % 3;
    const unsigned char* wb = lds + DW + (tap & 1) * 8192;
#pragma unroll
    for (int ks = 0; ks < 2; ++ks) {
      const int gran = ks * 4 + kgrp;
      int q = ky * 52 + xread + kx;
      bf16x8 afr = *(const bf16x8*)(lds + DA + q * 128 + ((gran ^ (q & 7)) << 4));
      bf16x8 bfr[4];
#pragma unroll
      for (int fn = 0; fn < 4; ++fn) {
        int co = fn * 16 + lrow;
        bfr[fn] = *(const bf16x8*)(wb + co * 128 + ((gran ^ (co & 7)) << 4));
      }
#pragma unroll
      for (int fn = 0; fn < 4; ++fn)
        acc[fn] = __builtin_amdgcn_mfma_f32_16x16x32_bf16(afr, bfr[fn], acc[fn],
                                                          0, 0, 0);
    }
    __syncthreads();
  }

  // ---- epilogue: BN + GELU -> hbuf [n][p][64] bf16 (direct stores) ----
  __bf16* hb = hbuf + ((size_t)n * P_PIX + r * WFEAT) * C_IN;
#pragma unroll
  for (int fn = 0; fn < 4; ++fn) {
    int co = fn * 16 + lrow;
    float sc = dh_g[co] / sqrtf(dh_v[co] + BEPS);
    float sh = dh_be[co] - dh_m[co] * sc + dh_b1[co] * sc;
#pragma unroll
    for (int rr = 0; rr < 4; ++rr) {
      int x = wid * 16 + kgrp * 4 + rr;
      if (x < WFEAT) {
        float val = gelu_exact(acc[fn][rr] * sc + sh);
        hb[(size_t)x * C_IN + co] = (__bf16)val;
      }
    }
  }
}

// ---------------- mid: depth logits + softmax + fp 1x1 conv ----------------
// LDS: MH h-tile 16384 | MX featT-tile 16384 | MWF 16384 | MW2 4096 | ML 16896
#define MH 0
#define MX 16384
#define MWF 32768
#define MW2 49152
#define ML 53248

__global__ __launch_bounds__(256) void k_mid(
    const __bf16* __restrict__ hbuf, const __bf16* __restrict__ featT,
    const float* __restrict__ dh_w2, const float* __restrict__ dh_b2,
    const float* __restrict__ fp_w, const float* __restrict__ fp_b,
    const float* __restrict__ fp_g, const float* __restrict__ fp_be,
    const float* __restrict__ fp_m, const float* __restrict__ fp_v,
    const float* __restrict__ trust, float* __restrict__ dp_t,
    float* __restrict__ fpn) {
  __shared__ __align__(16) unsigned char lds[70144];
  const int n = blockIdx.x / 11;
  const int tile = blockIdx.x % 11;
  const int p0 = tile * 128;
  const int tid = threadIdx.x;
  const int l = tid & 63;
  const int wid = tid >> 6;
  const int lrow = l & 15;
  const int kgrp = l >> 4;

  // ---- stage h tile and featT tile (bf16x8 granules, swizzled) ----
  for (int i = tid; i < 1024; i += 256) {
    int px = i >> 3, g = i & 7;
    int gp = p0 + px;
    bf16x8 hv, xv;
    if (gp < P_PIX) {
      hv = *(const bf16x8*)(hbuf + ((size_t)n * P_PIX + gp) * C_IN + g * 8);
      xv = *(const bf16x8*)(featT + ((size_t)n * P_PIX + gp) * C_IN + g * 8);
    } else {
      __bf16 z[8] = {};
      hv = *(bf16x8*)z;
      xv = hv;
    }
    int byte = px * 128 + ((g ^ (px & 7)) << 4);
    *(bf16x8*)(lds + MH + byte) = hv;
    *(bf16x8*)(lds + MX + byte) = xv;
  }
  // ---- stage Wfp (fp32 -> bf16) ----
  for (int i = tid; i < 1024; i += 256) {
    int co = i >> 3, g = i & 7;
    const float* sp = fp_w + co * 64 + g * 8;
    __bf16 tmp[8];
#pragma unroll
    for (int j = 0; j < 8; ++j) tmp[j] = (__bf16)sp[j];
    *(bf16x8*)(lds + MWF + co * 128 + ((g ^ (co & 7)) << 4)) = *(bf16x8*)tmp;
  }
  // ---- stage W2 ----
  if (tid < 256) {
    int d = tid >> 3, g = tid & 7;
    const float* sp = dh_w2 + d * 64 + g * 8;
    __bf16 tmp[8];
#pragma unroll
    for (int j = 0; j < 8; ++j) tmp[j] = (__bf16)sp[j];
    *(bf16x8*)(lds + MW2 + d * 128 + ((g ^ (d & 7)) << 4)) = *(bf16x8*)tmp;
  }
  __syncthreads();

  // ---- depth logits MFMA: M=128 N=32 K=64 ----
  f32x4 acc_l[2][2];
#pragma unroll
  for (int i = 0; i < 2; ++i)
#pragma unroll
    for (int j = 0; j < 2; ++j) acc_l[i][j] = {0.f, 0.f, 0.f, 0.f};
#pragma unroll
  for (int ks = 0; ks < 2; ++ks) {
    const int gran = ks * 4 + kgrp;
    bf16x8 afr[2], bfr[2];
#pragma unroll
    for (int fm = 0; fm < 2; ++fm) {
      int px = wid * 32 + fm * 16 + lrow;
      afr[fm] = *(const bf16x8*)(lds + MH + px * 128 + ((gran ^ (px & 7)) << 4));
    }
#pragma unroll
    for (int fn = 0; fn < 2; ++fn) {
      int d = fn * 16 + lrow;
      bfr[fn] = *(const bf16x8*)(lds + MW2 + d * 128 + ((gran ^ (d & 7)) << 4));
    }
#pragma unroll
    for (int fm = 0; fm < 2; ++fm)
#pragma unroll
      for (int fn = 0; fn < 2; ++fn)
        acc_l[fm][fn] = __builtin_amdgcn_mfma_f32_16x16x32_bf16(
            afr[fm], bfr[fn], acc_l[fm][fn], 0, 0, 0);
  }
  {
    float* lo = (float*)(lds + ML);
#pragma unroll
    for (int fn = 0; fn < 2; ++fn) {
      int d = fn * 16 + lrow;
      float b2v = dh_b2[d];
#pragma unroll
      for (int fm = 0; fm < 2; ++fm) {
#pragma unroll
        for (int rr = 0; rr < 4; ++rr) {
          int px = wid * 32 + fm * 16 + kgrp * 4 + rr;
          lo[px * 33 + d] = acc_l[fm][fn][rr] + b2v;
        }
      }
    }
  }

  // ---- fp 1x1 conv MFMA: M=128 N=128 K=64 ----
  f32x4 acc_fp[2][8];
#pragma unroll
  for (int i = 0; i < 2; ++i)
#pragma unroll
    for (int j = 0; j < 8; ++j) acc_fp[i][j] = {0.f, 0.f, 0.f, 0.f};
#pragma unroll
  for (int ks = 0; ks < 2; ++ks) {
    const int gran = ks * 4 + kgrp;
    bf16x8 afr[2], bfr[8];
#pragma unroll
    for (int fm = 0; fm < 2; ++fm) {
      int px = wid * 32 + fm * 16 + lrow;
      afr[fm] = *(const bf16x8*)(lds + MX + px * 128 + ((gran ^ (px & 7)) << 4));
    }
#pragma unroll
    for (int fn = 0; fn < 8; ++fn) {
      int co = fn * 16 + lrow;
      bfr[fn] = *(const bf16x8*)(lds + MWF + co * 128 + ((gran ^ (co & 7)) << 4));
    }
#pragma unroll
    for (int fm = 0; fm < 2; ++fm)
#pragma unroll
      for (int fn = 0; fn < 8; ++fn)
        acc_fp[fm][fn] = __builtin_amdgcn_mfma_f32_16x16x32_bf16(
            afr[fm], bfr[fn], acc_fp[fm][fn], 0, 0, 0);
  }
  __syncthreads();  // logits visible

  // ---- softmax (+trust fold) -> dp_t ----
  if (tid < 128 && p0 + tid < P_PIX) {
    const float* lo = (const float*)(lds + ML);
    float lg[ND];
#pragma unroll
    for (int d = 0; d < ND; ++d) lg[d] = lo[tid * 33 + d];
    float mx = lg[0];
#pragma unroll
    for (int d = 1; d < ND; ++d) mx = fmaxf(mx, lg[d]);
    float sum = 0.f;
#pragma unroll
    for (int d = 0; d < ND; ++d) {
      lg[d] = expf(lg[d] - mx);
      sum += lg[d];
    }
    float inv = trust[n] / sum;
    float* op = dp_t + ((size_t)n * P_PIX + p0 + tid) * ND;
#pragma unroll
    for (int d = 0; d < ND; ++d) op[d] = lg[d] * inv;
  }

  // ---- fp epilogue: BN + GELU -> fpn [n][p][128] f32 ----
#pragma unroll
  for (int fn = 0; fn < 8; ++fn) {
    int co = fn * 16 + lrow;
    float sc = fp_g[co] / sqrtf(fp_v[co] + BEPS);
    float sh = fp_be[co] - fp_m[co] * sc + fp_b[co] * sc;
#pragma unroll
    for (int fm = 0; fm < 2; ++fm) {
#pragma unroll
      for (int rr = 0; rr < 4; ++rr) {
        int px = wid * 32 + fm * 16 + kgrp * 4 + rr;
        if (p0 + px < P_PIX) {
          float val = gelu_exact(acc_fp[fm][fn][rr] * sc + sh);
          fpn[((size_t)n * P_PIX + p0 + px) * CB + co] = val;
        }
      }
    }
  }
}

// ---------------- ray-factored scatter (unchanged) ----------------
__global__ __launch_bounds__(256) void k_rayscatter(
    const float* __restrict__ fpn, const float* __restrict__ dp_t,
    const float* __restrict__ Kmat, const float* __restrict__ Tmat,
    float* __restrict__ bev) {
  __shared__ float dpL[28][32];
  __shared__ float FL[28][128];
  __shared__ float G[32][132];
  __shared__ int colL[32], rowL[32], vL[32];

  const int n = blockIdx.x / 50;
  const int xc = blockIdx.x % 50;
  const int tid = threadIdx.x;
  const int npb = n * P_PIX + xc;

  for (int i = tid; i < 28 * 32; i += 256) {
    int r = i >> 5, d = i & 31;
    dpL[r][d] = dp_t[((size_t)(npb + r * 50)) * ND + d];
  }
  for (int i = tid; i < 28 * 32; i += 256) {
    int r = i >> 5, c4 = i & 31;
    *(float4*)&FL[r][c4 * 4] =
        *(const float4*)(fpn + ((size_t)(npb + r * 50)) * CB + c4 * 4);
  }
  if (tid < 32) {
    int d = tid;
    const float* Kp = Kmat + n * 9;
    float fx = Kp[0], cx = Kp[2];
    float rx = ((float)xc - cx) / fx;
    const float* Tp = Tmat + n * 16;
    float depth = 1.0f + (float)d * (49.0f / 31.0f);
    float pcx = rx * depth, pcz = depth;
    float Xx = Tp[0] * pcx + Tp[2] * pcz + Tp[3];
    float Xy = Tp[4] * pcx + Tp[6] * pcz + Tp[7];
    float uf = (Xx + 20.0f) / 40.0f * 127.0f;
    float vf = (Xy + 20.0f) / 40.0f * 127.0f;
    vL[d] = (uf > -1.0f && uf < 128.0f && vf > -1.0f && vf < 128.0f) ? 1 : 0;
    colL[d] = (int)uf;
    rowL[d] = (int)vf;
  }
  __syncthreads();

  {
    const int d = tid >> 3, cg = tid & 7;
    float a[16];
#pragma unroll
    for (int j = 0; j < 16; ++j) a[j] = 0.f;
    for (int r = 0; r < 28; ++r) {
      float dv = dpL[r][d];
      const float* fr = &FL[r][cg * 16];
#pragma unroll
      for (int j = 0; j < 16; ++j) a[j] = fmaf(dv, fr[j], a[j]);
    }
    float* gw = &G[d][cg * 16];
#pragma unroll
    for (int j = 0; j < 16; ++j) gw[j] = a[j];
  }
  __syncthreads();

  {
    const int hd = tid >> 7;
    const int c = tid & 127;
    const int b = n / 6;
    float* bb = bev + ((size_t)b * (BH * BW)) * CB + c;
    for (int d0 = 0; d0 < ND; d0 += 2) {
      int d = d0 + hd;
      if (vL[d])
        atomicAdd(bb + ((size_t)rowL[d] * BW + colL[d]) * CB, G[d][c]);
    }
  }
}

// ---------------- BEV 3x3 conv via bf16 MFMA (unchanged) ----------------
template <int IN_F32, int OUT_NCHW>
__global__ __launch_bounds__(256) void k_bev_conv_mfma(
    const void* __restrict__ inp, const __bf16* __restrict__ wt,
    const float* __restrict__ bias, const float* __restrict__ g,
    const float* __restrict__ be, const float* __restrict__ m,
    const float* __restrict__ v, void* __restrict__ outp) {
  __shared__ __align__(16) unsigned char ldsA[10 * 10 * CB * 2];
  __shared__ __align__(16) unsigned char ldsB[64 * 130 * 4];

  const int blk = blockIdx.x;
  const int tx = blk % 16;
  const int ty = (blk / 16) % 16;
  const int b = blk / 256;
  const int y0 = ty * 8, x0 = tx * 8;

  const int l = threadIdx.x & 63;
  const int wid = threadIdx.x >> 6;
  const int wm = wid & 1;
  const int wn = wid >> 1;

  for (int i = threadIdx.x; i < 1600; i += 256) {
    int q = i >> 4;
    int ch = i & 15;
    int hy = q / 10, hx = q % 10;
    int gy = y0 + hy - 1, gx = x0 + hx - 1;
    bf16x8 val;
    if (gy >= 0 && gy < BH && gx >= 0 && gx < BW) {
      if (IN_F32) {
        const float* ib = (const float*)inp + (size_t)b * BH * BW * CB;
        const float* sp = ib + ((size_t)gy * BW + gx) * CB + ch * 8;
        float4 a = *(const float4*)sp;
        float4 bb = *(const float4*)(sp + 4);
        __bf16 tmp[8] = {(__bf16)a.x,  (__bf16)a.y,  (__bf16)a.z,  (__bf16)a.w,
                         (__bf16)bb.x, (__bf16)bb.y, (__bf16)bb.z, (__bf16)bb.w};
        val = *(bf16x8*)tmp;
      } else {
        const __bf16* ib = (const __bf16*)inp + (size_t)b * BH * BW * CB;
        val = *(const bf16x8*)(ib + ((size_t)gy * BW + gx) * CB + ch * 8);
      }
    } else {
      __bf16 tmp[8] = {(__bf16)0.f, (__bf16)0.f, (__bf16)0.f, (__bf16)0.f,
                       (__bf16)0.f, (__bf16)0.f, (__bf16)0.f, (__bf16)0.f};
      val = *(bf16x8*)tmp;
    }
    int byte = (q * 256 + ch * 16) ^ ((q & 7) << 4);
    *(bf16x8*)(ldsA + byte) = val;
  }
  __syncthreads();

  f32x4 acc[2][4];
#pragma unroll
  for (int i = 0; i < 2; ++i)
#pragma unroll
    for (int j = 0; j < 4; ++j) acc[i][j] = {0.f, 0.f, 0.f, 0.f};

  const int lrow = l & 15;
  const int kgrp = l >> 4;

  for (int tap = 0; tap < 9; ++tap) {
    if (tap) __syncthreads();
    {
      const __bf16* wp = wt + (size_t)tap * CB * CB;
      for (int i = threadIdx.x; i < 2048; i += 256) {
        int co = i >> 4;
        int ch = i & 15;
        uint4 val = *(const uint4*)(wp + co * CB + ch * 8);
        int byte = (co * 256 + ch * 16) ^ ((co & 7) << 4);
        *(uint4*)(ldsB + byte) = val;
      }
    }
    __syncthreads();

    const int ky = tap / 3, kx = tap % 3;
#pragma unroll
    for (int ks = 0; ks < 4; ++ks) {
      const int ci0b = (ks * 32 + kgrp * 8) * 2;
      bf16x8 afr[2], bfr[4];
#pragma unroll
      for (int fm = 0; fm < 2; ++fm) {
        int mpx = wm * 32 + fm * 16 + lrow;
        int q = (mpx / 8 + ky) * 10 + (mpx % 8 + kx);
        int byte = (q * 256 + ci0b) ^ ((q & 7) << 4);
        afr[fm] = *(const bf16x8*)(ldsA + byte);
      }
#pragma unroll
      for (int fn = 0; fn < 4; ++fn) {
        int r = wn * 64 + fn * 16 + lrow;
        int byte = (r * 256 + ci0b) ^ ((r & 7) << 4);
        bfr[fn] = *(const bf16x8*)(ldsB + byte);
      }
#pragma unroll
      for (int fm = 0; fm < 2; ++fm)
#pragma unroll
        for (int fn = 0; fn < 4; ++fn)
          acc[fm][fn] = __builtin_amdgcn_mfma_f32_16x16x32_bf16(
              afr[fm], bfr[fn], acc[fm][fn], 0, 0, 0);
    }
  }

  if (OUT_NCHW == 0) {
    __bf16* out = (__bf16*)outp;
#pragma unroll
    for (int fn = 0; fn < 4; ++fn) {
      int co = wn * 64 + fn * 16 + lrow;
      float sc = g[co] / sqrtf(v[co] + BEPS);
      float sh = be[co] - m[co] * sc + bias[co] * sc;
#pragma unroll
      for (int fm = 0; fm < 2; ++fm) {
#pragma unroll
        for (int r = 0; r < 4; ++r) {
          int mpx = wm * 32 + fm * 16 + kgrp * 4 + r;
          int y = y0 + mpx / 8, x = x0 + mpx % 8;
          float val = gelu_exact(acc[fm][fn][r] * sc + sh);
          out[((size_t)(b * BH + y) * BW + x) * CB + co] = (__bf16)val;
        }
      }
    }
  } else {
    __syncthreads();
    float* lo = (float*)ldsB;
#pragma unroll
    for (int fn = 0; fn < 4; ++fn) {
      int co = wn * 64 + fn * 16 + lrow;
      float sc = g[co] / sqrtf(v[co] + BEPS);
      float sh = be[co] - m[co] * sc + bias[co] * sc;
#pragma unroll
      for (int fm = 0; fm < 2; ++fm) {
#pragma unroll
        for (int r = 0; r < 4; ++r) {
          int mpx = wm * 32 + fm * 16 + kgrp * 4 + r;
          lo[mpx * 130 + co] = gelu_exact(acc[fm][fn][r] * sc + sh);
        }
      }
    }
    __syncthreads();
    float* out = (float*)outp;
    for (int pair = threadIdx.x; pair < 1024; pair += 256) {
      int co = pair >> 3, py = pair & 7;
      float tmp[8];
#pragma unroll
      for (int i = 0; i < 8; ++i) tmp[i] = lo[(py * 8 + i) * 130 + co];
      float* op = out + (((size_t)(b * CB + co) * BH) + (y0 + py)) * BW + x0;
      *(float4*)op = *(float4*)tmp;
      *(float4*)(op + 4) = *(float4*)(tmp + 4);
    }
  }
}

extern "C" void kernel_launch(void* const* d_in, const int* in_sizes, int n_in,
                              void* d_out, int out_size, void* d_ws, size_t ws_size,
                              hipStream_t stream) {
  const float* feat = (const float*)d_in[0];
  const float* Kmat = (const float*)d_in[1];
  const float* Tmat = (const float*)d_in[2];
  const float* trust = (const float*)d_in[3];
  const float* dh_w1 = (const float*)d_in[4];
  const float* dh_b1 = (const float*)d_in[5];
  const float* dh_g = (const float*)d_in[6];
  const float* dh_be = (const float*)d_in[7];
  const float* dh_m = (const float*)d_in[8];
  const float* dh_v = (const float*)d_in[9];
  const float* dh_w2 = (const float*)d_in[10];
  const float* dh_b2 = (const float*)d_in[11];
  const float* fp_w = (const float*)d_in[12];
  const float* fp_b = (const float*)d_in[13];
  const float* fp_g = (const float*)d_in[14];
  const float* fp_be = (const float*)d_in[15];
  const float* fp_m = (const float*)d_in[16];
  const float* fp_v = (const float*)d_in[17];
  const float* br_w1 = (const float*)d_in[18];
  const float* br_b1 = (const float*)d_in[19];
  const float* br_g1 = (const float*)d_in[20];
  const float* br_be1 = (const float*)d_in[21];
  const float* br_m1 = (const float*)d_in[22];
  const float* br_v1 = (const float*)d_in[23];
  const float* br_w2 = (const float*)d_in[24];
  const float* br_b2 = (const float*)d_in[25];
  const float* br_g2 = (const float*)d_in[26];
  const float* br_be2 = (const float*)d_in[27];
  const float* br_m2 = (const float*)d_in[28];
  const float* br_v2 = (const float*)d_in[29];

  float* ws = (float*)d_ws;
  float* dp_t = ws;                          // 537,600 f
  float* fpn = dp_t + 537600;                // 2,150,400 f
  float* bev = fpn + 2150400;                // 4,194,304 f (fp32 NHWC accum)
  float* after_bev = bev + 4194304;
  __bf16* h1bf = (__bf16*)after_bev;                        // 4,194,304 bf16
  __bf16* w1dh = (__bf16*)(after_bev + 2097152);            // 36,864 bf16
  __bf16* w1bev = (__bf16*)(after_bev + 2097152 + 18432);   // 147,456 bf16
  __bf16* w2bev = (__bf16*)(after_bev + 2097152 + 18432 + 73728);
  __bf16* featT = (__bf16*)(after_bev + 2097152 + 18432 + 2 * 73728);  // 1,075,200 bf16
  __bf16* hbuf = featT + 1075200;                            // 1,075,200 bf16

  // fused weight preps
  k_wprep_all<<<(9 * 64 * 64 + 2 * 9 * CB * CB + 255) / 256, 256, 0, stream>>>(
      dh_w1, br_w1, br_w2, w1dh, w1bev, w2bev);
  // feat layout transform NCHW f32 -> NHWC bf16
  k_transpose<<<N_IMG * 22, 256, 0, stream>>>(feat, featT);
  // zero BEV accumulator
  hipMemsetAsync(bev, 0, (size_t)2 * BH * BW * CB * sizeof(float), stream);
  // depth-head conv (336 blocks)
  k_dh<<<N_IMG * HFEAT, 256, 0, stream>>>(featT, w1dh, dh_b1, dh_g, dh_be,
                                          dh_m, dh_v, hbuf);
  // logits + softmax + feature projection (132 blocks)
  k_mid<<<N_IMG * 11, 256, 0, stream>>>(hbuf, featT, dh_w2, dh_b2, fp_w, fp_b,
                                        fp_g, fp_be, fp_m, fp_v, trust, dp_t,
                                        fpn);
  // ray-factored scatter
  k_rayscatter<<<N_IMG * WFEAT, 256, 0, stream>>>(fpn, dp_t, Kmat, Tmat, bev);
  // BEV refinement convs via MFMA
  k_bev_conv_mfma<1, 0><<<2 * 16 * 16, 256, 0, stream>>>(
      (const void*)bev, w1bev, br_b1, br_g1, br_be1, br_m1, br_v1, (void*)h1bf);
  k_bev_conv_mfma<0, 1><<<2 * 16 * 16, 256, 0, stream>>>(
      (const void*)h1bf, w2bev, br_b2, br_g2, br_be2, br_m2, br_v2, d_out);
}

// Round 7
// 185.170 us; speedup vs baseline: 1.0078x; 1.0078x over previous
//
#include <hip/hip_runtime.h>
#include <math.h>

#define N_IMG 12
#define C_IN 64
#define HFEAT 28
#define WFEAT 50
#define P_PIX 1400
#define ND 32
#define CB 128
#define BH 128
#define BW 128
#define BEPS 1e-5f

typedef float f32x4 __attribute__((ext_vector_type(4)));
typedef __bf16 bf16x8 __attribute__((ext_vector_type(8)));

__device__ __forceinline__ float gelu_exact(float x) {
  return 0.5f * x * (1.0f + erff(x * 0.70710678118654752440f));
}

// ---------------- prep: weight preps + feat NCHW->NHWC bf16, one kernel ------
// blocks [0,264): transpose; blocks [264, 264+1296): weight prep
__global__ __launch_bounds__(256) void k_prep(
    const float* __restrict__ feat, const float* __restrict__ dh_w1,
    const float* __restrict__ br_w1, const float* __restrict__ br_w2,
    __bf16* __restrict__ featT, __bf16* __restrict__ w1dh,
    __bf16* __restrict__ w1bev, __bf16* __restrict__ w2bev) {
  if (blockIdx.x < 264) {
    __shared__ float t[64][65];
    const int n = blockIdx.x / 22;
    const int p0 = (blockIdx.x % 22) * 64;
    const float* fb = feat + (size_t)n * C_IN * P_PIX;
    const int lane = threadIdx.x & 63;
    const int grp = threadIdx.x >> 6;
#pragma unroll
    for (int j = 0; j < 16; ++j) {
      int ci = j * 4 + grp;
      int px = p0 + lane;
      t[ci][lane] = (px < P_PIX) ? fb[ci * P_PIX + px] : 0.f;
    }
    __syncthreads();
#pragma unroll
    for (int k = 0; k < 2; ++k) {
      int gid = threadIdx.x * 2 + k;
      int pxl = gid >> 3, g = gid & 7;
      int px = p0 + pxl;
      if (px < P_PIX) {
        __bf16 tmp[8];
#pragma unroll
        for (int j = 0; j < 8; ++j) tmp[j] = (__bf16)t[g * 8 + j][pxl];
        *(bf16x8*)(featT + ((size_t)n * P_PIX + px) * C_IN + g * 8) = *(bf16x8*)tmp;
      }
    }
  } else {
    int idx = (blockIdx.x - 264) * 256 + threadIdx.x;
    if (idx < 9 * 64 * 64) {
      int ci = idx & 63, co = (idx >> 6) & 63, tap = idx >> 12;
      w1dh[idx] = (__bf16)dh_w1[(co * 64 + ci) * 9 + tap];
    } else if (idx < 9 * 64 * 64 + 9 * CB * CB) {
      int k = idx - 9 * 64 * 64;
      int ci = k % CB, co = (k / CB) % CB, tap = k / (CB * CB);
      w1bev[k] = (__bf16)br_w1[((size_t)co * CB + ci) * 9 + tap];
    } else if (idx < 9 * 64 * 64 + 2 * 9 * CB * CB) {
      int k = idx - 9 * 64 * 64 - 9 * CB * CB;
      int ci = k % CB, co = (k / CB) % CB, tap = k / (CB * CB);
      w2bev[k] = (__bf16)br_w2[((size_t)co * CB + ci) * 9 + tap];
    }
  }
}

// ---------------- depth-head 3x3 conv via MFMA, one block per (image,row) ----
// LDS: A [0,19968) 3 rows x 52 x 64ci bf16 swizzled; W dbuf [19968, +2*8192)
// After compute, A region is reused as the h-repack buffer (coalesced stores).
#define DA 0
#define DW 19968

__global__ __launch_bounds__(256) void k_dh(
    const __bf16* __restrict__ featT, const __bf16* __restrict__ w1bf,
    const float* __restrict__ dh_b1, const float* __restrict__ dh_g,
    const float* __restrict__ dh_be, const float* __restrict__ dh_m,
    const float* __restrict__ dh_v, __bf16* __restrict__ hbuf) {
  __shared__ __align__(16) unsigned char lds[19968 + 2 * 8192];
  const int n = blockIdx.x / HFEAT;
  const int r = blockIdx.x % HFEAT;
  const int tid = threadIdx.x;
  const int l = tid & 63;
  const int wid = tid >> 6;
  const int lrow = l & 15;
  const int kgrp = l >> 4;

  // ---- stage A: rows r-1..r+1, xcols -1..50, 64 ci ----
  {
    const __bf16* fT = featT + (size_t)n * P_PIX * C_IN;
    for (int i = tid; i < 1248; i += 256) {
      int q = i >> 3, g = i & 7;
      int hrow = q / 52, hx = q % 52;
      int gy = r - 1 + hrow, gx = hx - 1;
      bf16x8 val;
      if (gy >= 0 && gy < HFEAT && gx >= 0 && gx < WFEAT) {
        val = *(const bf16x8*)(fT + ((size_t)(gy * WFEAT + gx)) * C_IN + g * 8);
      } else {
        __bf16 z[8] = {};
        val = *(bf16x8*)z;
      }
      *(bf16x8*)(lds + DA + q * 128 + ((g ^ (q & 7)) << 4)) = val;
    }
  }
  // ---- stage W tap 0 into buf 0 ----
  for (int i = tid; i < 512; i += 256) {
    int co = i >> 3, g = i & 7;
    uint4 val = *(const uint4*)(w1bf + co * 64 + g * 8);
    *(uint4*)(lds + DW + co * 128 + ((g ^ (co & 7)) << 4)) = val;
  }
  __syncthreads();

  const int px_local = wid * 16 + lrow;
  const int xread = px_local < 50 ? px_local : 49;

  f32x4 acc[4];
#pragma unroll
  for (int j = 0; j < 4; ++j) acc[j] = {0.f, 0.f, 0.f, 0.f};

  for (int tap = 0; tap < 9; ++tap) {
    if (tap < 8) {
      const __bf16* wp = w1bf + (size_t)(tap + 1) * 4096;
      unsigned char* wb = lds + DW + ((tap + 1) & 1) * 8192;
      for (int i = tid; i < 512; i += 256) {
        int co = i >> 3, g = i & 7;
        uint4 val = *(const uint4*)(wp + co * 64 + g * 8);
        *(uint4*)(wb + co * 128 + ((g ^ (co & 7)) << 4)) = val;
      }
    }
    const int ky = tap / 3, kx = tap % 3;
    const unsigned char* wb = lds + DW + (tap & 1) * 8192;
#pragma unroll
    for (int ks = 0; ks < 2; ++ks) {
      const int gran = ks * 4 + kgrp;
      int q = ky * 52 + xread + kx;
      bf16x8 afr = *(const bf16x8*)(lds + DA + q * 128 + ((gran ^ (q & 7)) << 4));
      bf16x8 bfr[4];
#pragma unroll
      for (int fn = 0; fn < 4; ++fn) {
        int co = fn * 16 + lrow;
        bfr[fn] = *(const bf16x8*)(wb + co * 128 + ((gran ^ (co & 7)) << 4));
      }
#pragma unroll
      for (int fn = 0; fn < 4; ++fn)
        acc[fn] = __builtin_amdgcn_mfma_f32_16x16x32_bf16(afr, bfr[fn], acc[fn],
                                                          0, 0, 0);
    }
    __syncthreads();
  }

  // ---- epilogue: BN + GELU -> LDS repack (bf16, swizzled) ----
#pragma unroll
  for (int fn = 0; fn < 4; ++fn) {
    int co = fn * 16 + lrow;
    float sc = dh_g[co] / sqrtf(dh_v[co] + BEPS);
    float sh = dh_be[co] - dh_m[co] * sc + dh_b1[co] * sc;
#pragma unroll
    for (int rr = 0; rr < 4; ++rr) {
      int x = wid * 16 + kgrp * 4 + rr;
      float val = gelu_exact(acc[fn][rr] * sc + sh);
      *(__bf16*)(lds + DA + x * 128 + ((co * 2) ^ ((x & 7) << 4))) = (__bf16)val;
    }
  }
  __syncthreads();
  // ---- coalesced copy: 50 px x 64co bf16 -> hbuf ----
  {
    __bf16* hb = hbuf + ((size_t)n * P_PIX + r * WFEAT) * C_IN;
    for (int i = tid; i < 400; i += 256) {
      int px = i >> 3, g = i & 7;
      bf16x8 v = *(const bf16x8*)(lds + DA + px * 128 + ((g * 16) ^ ((px & 7) << 4)));
      *(bf16x8*)(hb + (size_t)px * C_IN + g * 8) = v;
    }
  }
}

// ---------------- mid: depth logits + softmax + fp 1x1 conv ----------------
// LDS: MH 0..16K h-tile | MX 16K..32K featT-tile | MWF 32K..48K | MW2 48K..52K
// | ML 53248.. logits/probs [128][33] f32.  After GEMMs, [0,32K) reused as
// bf16 FP tile [128px][128co] for coalesced output stores.
#define MH 0
#define MX 16384
#define MWF 32768
#define MW2 49152
#define ML 53248

__global__ __launch_bounds__(256) void k_mid(
    const __bf16* __restrict__ hbuf, const __bf16* __restrict__ featT,
    const float* __restrict__ dh_w2, const float* __restrict__ dh_b2,
    const float* __restrict__ fp_w, const float* __restrict__ fp_b,
    const float* __restrict__ fp_g, const float* __restrict__ fp_be,
    const float* __restrict__ fp_m, const float* __restrict__ fp_v,
    const float* __restrict__ trust, float* __restrict__ dp_t,
    __bf16* __restrict__ fpnb) {
  __shared__ __align__(16) unsigned char lds[70144];
  const int n = blockIdx.x / 11;
  const int tile = blockIdx.x % 11;
  const int p0 = tile * 128;
  const int tid = threadIdx.x;
  const int l = tid & 63;
  const int wid = tid >> 6;
  const int lrow = l & 15;
  const int kgrp = l >> 4;

  // ---- stage h tile and featT tile ----
  for (int i = tid; i < 1024; i += 256) {
    int px = i >> 3, g = i & 7;
    int gp = p0 + px;
    bf16x8 hv, xv;
    if (gp < P_PIX) {
      hv = *(const bf16x8*)(hbuf + ((size_t)n * P_PIX + gp) * C_IN + g * 8);
      xv = *(const bf16x8*)(featT + ((size_t)n * P_PIX + gp) * C_IN + g * 8);
    } else {
      __bf16 z[8] = {};
      hv = *(bf16x8*)z;
      xv = hv;
    }
    int byte = px * 128 + ((g ^ (px & 7)) << 4);
    *(bf16x8*)(lds + MH + byte) = hv;
    *(bf16x8*)(lds + MX + byte) = xv;
  }
  // ---- stage Wfp (fp32 -> bf16) ----
  for (int i = tid; i < 1024; i += 256) {
    int co = i >> 3, g = i & 7;
    const float* sp = fp_w + co * 64 + g * 8;
    __bf16 tmp[8];
#pragma unroll
    for (int j = 0; j < 8; ++j) tmp[j] = (__bf16)sp[j];
    *(bf16x8*)(lds + MWF + co * 128 + ((g ^ (co & 7)) << 4)) = *(bf16x8*)tmp;
  }
  // ---- stage W2 ----
  if (tid < 256) {
    int d = tid >> 3, g = tid & 7;
    const float* sp = dh_w2 + d * 64 + g * 8;
    __bf16 tmp[8];
#pragma unroll
    for (int j = 0; j < 8; ++j) tmp[j] = (__bf16)sp[j];
    *(bf16x8*)(lds + MW2 + d * 128 + ((g ^ (d & 7)) << 4)) = *(bf16x8*)tmp;
  }
  __syncthreads();

  // ---- depth logits MFMA: M=128 N=32 K=64 ----
  f32x4 acc_l[2][2];
#pragma unroll
  for (int i = 0; i < 2; ++i)
#pragma unroll
    for (int j = 0; j < 2; ++j) acc_l[i][j] = {0.f, 0.f, 0.f, 0.f};
#pragma unroll
  for (int ks = 0; ks < 2; ++ks) {
    const int gran = ks * 4 + kgrp;
    bf16x8 afr[2], bfr[2];
#pragma unroll
    for (int fm = 0; fm < 2; ++fm) {
      int px = wid * 32 + fm * 16 + lrow;
      afr[fm] = *(const bf16x8*)(lds + MH + px * 128 + ((gran ^ (px & 7)) << 4));
    }
#pragma unroll
    for (int fn = 0; fn < 2; ++fn) {
      int d = fn * 16 + lrow;
      bfr[fn] = *(const bf16x8*)(lds + MW2 + d * 128 + ((gran ^ (d & 7)) << 4));
    }
#pragma unroll
    for (int fm = 0; fm < 2; ++fm)
#pragma unroll
      for (int fn = 0; fn < 2; ++fn)
        acc_l[fm][fn] = __builtin_amdgcn_mfma_f32_16x16x32_bf16(
            afr[fm], bfr[fn], acc_l[fm][fn], 0, 0, 0);
  }
  {
    float* lo = (float*)(lds + ML);
#pragma unroll
    for (int fn = 0; fn < 2; ++fn) {
      int d = fn * 16 + lrow;
      float b2v = dh_b2[d];
#pragma unroll
      for (int fm = 0; fm < 2; ++fm) {
#pragma unroll
        for (int rr = 0; rr < 4; ++rr) {
          int px = wid * 32 + fm * 16 + kgrp * 4 + rr;
          lo[px * 33 + d] = acc_l[fm][fn][rr] + b2v;
        }
      }
    }
  }

  // ---- fp 1x1 conv MFMA: M=128 N=128 K=64 ----
  f32x4 acc_fp[2][8];
#pragma unroll
  for (int i = 0; i < 2; ++i)
#pragma unroll
    for (int j = 0; j < 8; ++j) acc_fp[i][j] = {0.f, 0.f, 0.f, 0.f};
#pragma unroll
  for (int ks = 0; ks < 2; ++ks) {
    const int gran = ks * 4 + kgrp;
    bf16x8 afr[2], bfr[8];
#pragma unroll
    for (int fm = 0; fm < 2; ++fm) {
      int px = wid * 32 + fm * 16 + lrow;
      afr[fm] = *(const bf16x8*)(lds + MX + px * 128 + ((gran ^ (px & 7)) << 4));
    }
#pragma unroll
    for (int fn = 0; fn < 8; ++fn) {
      int co = fn * 16 + lrow;
      bfr[fn] = *(const bf16x8*)(lds + MWF + co * 128 + ((gran ^ (co & 7)) << 4));
    }
#pragma unroll
    for (int fm = 0; fm < 2; ++fm)
#pragma unroll
      for (int fn = 0; fn < 8; ++fn)
        acc_fp[fm][fn] = __builtin_amdgcn_mfma_f32_16x16x32_bf16(
            afr[fm], bfr[fn], acc_fp[fm][fn], 0, 0, 0);
  }
  __syncthreads();  // all GEMM LDS reads done; ML logits visible

  // ---- fp epilogue: BN + GELU -> bf16 FP tile in LDS [0,32K) (swizzled) ----
#pragma unroll
  for (int fn = 0; fn < 8; ++fn) {
    int co = fn * 16 + lrow;
    float sc = fp_g[co] / sqrtf(fp_v[co] + BEPS);
    float sh = fp_be[co] - fp_m[co] * sc + fp_b[co] * sc;
#pragma unroll
    for (int fm = 0; fm < 2; ++fm) {
#pragma unroll
      for (int rr = 0; rr < 4; ++rr) {
        int px = wid * 32 + fm * 16 + kgrp * 4 + rr;
        float val = gelu_exact(acc_fp[fm][fn][rr] * sc + sh);
        *(__bf16*)(lds + px * 256 + ((co * 2) ^ ((px & 7) << 4))) = (__bf16)val;
      }
    }
  }
  // ---- softmax (+trust fold), probs written in place into ML ----
  if (tid < 128 && p0 + tid < P_PIX) {
    float* lo = (float*)(lds + ML);
    float lg[ND];
#pragma unroll
    for (int d = 0; d < ND; ++d) lg[d] = lo[tid * 33 + d];
    float mx = lg[0];
#pragma unroll
    for (int d = 1; d < ND; ++d) mx = fmaxf(mx, lg[d]);
    float sum = 0.f;
#pragma unroll
    for (int d = 0; d < ND; ++d) {
      lg[d] = expf(lg[d] - mx);
      sum += lg[d];
    }
    float inv = trust[n] / sum;
#pragma unroll
    for (int d = 0; d < ND; ++d) lo[tid * 33 + d] = lg[d] * inv;
  }
  __syncthreads();

  // ---- coalesced output copies ----
  // fpn: 128px x 128co bf16 = 2048 granules
  {
    for (int k = 0; k < 8; ++k) {
      int i = tid + k * 256;
      int px = i >> 4, g = i & 15;
      if (p0 + px < P_PIX) {
        bf16x8 v = *(const bf16x8*)(lds + px * 256 + ((g * 16) ^ ((px & 7) << 4)));
        *(bf16x8*)(fpnb + ((size_t)n * P_PIX + p0 + px) * CB + g * 8) = v;
      }
    }
  }
  // dp_t: 128px x 32d f32 = 1024 float4s
  {
    const float* lo = (const float*)(lds + ML);
    for (int k = 0; k < 4; ++k) {
      int j = tid + k * 256;
      int px = j >> 3, d0 = (j & 7) * 4;
      if (p0 + px < P_PIX) {
        float4 v;
        v.x = lo[px * 33 + d0];
        v.y = lo[px * 33 + d0 + 1];
        v.z = lo[px * 33 + d0 + 2];
        v.w = lo[px * 33 + d0 + 3];
        *(float4*)(dp_t + ((size_t)n * P_PIX + p0 + px) * ND + d0) = v;
      }
    }
  }
}

// ---------------- ray-factored scatter (fpn now bf16) ----------------
__global__ __launch_bounds__(256) void k_rayscatter(
    const __bf16* __restrict__ fpnb, const float* __restrict__ dp_t,
    const float* __restrict__ Kmat, const float* __restrict__ Tmat,
    float* __restrict__ bev) {
  __shared__ float dpL[28][32];
  __shared__ float FL[28][128];
  __shared__ float G[32][132];
  __shared__ int colL[32], rowL[32], vL[32];

  const int n = blockIdx.x / 50;
  const int xc = blockIdx.x % 50;
  const int tid = threadIdx.x;
  const int npb = n * P_PIX + xc;

  for (int i = tid; i < 28 * 32; i += 256) {
    int r = i >> 5, d = i & 31;
    dpL[r][d] = dp_t[((size_t)(npb + r * 50)) * ND + d];
  }
  for (int i = tid; i < 28 * 16; i += 256) {
    int r = i >> 4, gg = i & 15;
    bf16x8 v = *(const bf16x8*)(fpnb + ((size_t)(npb + r * 50)) * CB + gg * 8);
#pragma unroll
    for (int j = 0; j < 8; ++j) FL[r][gg * 8 + j] = (float)v[j];
  }
  if (tid < 32) {
    int d = tid;
    const float* Kp = Kmat + n * 9;
    float fx = Kp[0], cx = Kp[2];
    float rx = ((float)xc - cx) / fx;
    const float* Tp = Tmat + n * 16;
    float depth = 1.0f + (float)d * (49.0f / 31.0f);
    float pcx = rx * depth, pcz = depth;
    float Xx = Tp[0] * pcx + Tp[2] * pcz + Tp[3];
    float Xy = Tp[4] * pcx + Tp[6] * pcz + Tp[7];
    float uf = (Xx + 20.0f) / 40.0f * 127.0f;
    float vf = (Xy + 20.0f) / 40.0f * 127.0f;
    vL[d] = (uf > -1.0f && uf < 128.0f && vf > -1.0f && vf < 128.0f) ? 1 : 0;
    colL[d] = (int)uf;
    rowL[d] = (int)vf;
  }
  __syncthreads();

  {
    const int d = tid >> 3, cg = tid & 7;
    float a[16];
#pragma unroll
    for (int j = 0; j < 16; ++j) a[j] = 0.f;
    for (int r = 0; r < 28; ++r) {
      float dv = dpL[r][d];
      const float* fr = &FL[r][cg * 16];
#pragma unroll
      for (int j = 0; j < 16; ++j) a[j] = fmaf(dv, fr[j], a[j]);
    }
    float* gw = &G[d][cg * 16];
#pragma unroll
    for (int j = 0; j < 16; ++j) gw[j] = a[j];
  }
  __syncthreads();

  {
    const int hd = tid >> 7;
    const int c = tid & 127;
    const int b = n / 6;
    float* bb = bev + ((size_t)b * (BH * BW)) * CB + c;
    for (int d0 = 0; d0 < ND; d0 += 2) {
      int d = d0 + hd;
      if (vL[d])
        atomicAdd(bb + ((size_t)rowL[d] * BW + colL[d]) * CB, G[d][c]);
    }
  }
}

// ---------------- BEV 3x3 conv via bf16 MFMA (unchanged) ----------------
template <int IN_F32, int OUT_NCHW>
__global__ __launch_bounds__(256) void k_bev_conv_mfma(
    const void* __restrict__ inp, const __bf16* __restrict__ wt,
    const float* __restrict__ bias, const float* __restrict__ g,
    const float* __restrict__ be, const float* __restrict__ m,
    const float* __restrict__ v, void* __restrict__ outp) {
  __shared__ __align__(16) unsigned char ldsA[10 * 10 * CB * 2];
  __shared__ __align__(16) unsigned char ldsB[64 * 130 * 4];

  const int blk = blockIdx.x;
  const int tx = blk % 16;
  const int ty = (blk / 16) % 16;
  const int b = blk / 256;
  const int y0 = ty * 8, x0 = tx * 8;

  const int l = threadIdx.x & 63;
  const int wid = threadIdx.x >> 6;
  const int wm = wid & 1;
  const int wn = wid >> 1;

  for (int i = threadIdx.x; i < 1600; i += 256) {
    int q = i >> 4;
    int ch = i & 15;
    int hy = q / 10, hx = q % 10;
    int gy = y0 + hy - 1, gx = x0 + hx - 1;
    bf16x8 val;
    if (gy >= 0 && gy < BH && gx >= 0 && gx < BW) {
      if (IN_F32) {
        const float* ib = (const float*)inp + (size_t)b * BH * BW * CB;
        const float* sp = ib + ((size_t)gy * BW + gx) * CB + ch * 8;
        float4 a = *(const float4*)sp;
        float4 bb = *(const float4*)(sp + 4);
        __bf16 tmp[8] = {(__bf16)a.x,  (__bf16)a.y,  (__bf16)a.z,  (__bf16)a.w,
                         (__bf16)bb.x, (__bf16)bb.y, (__bf16)bb.z, (__bf16)bb.w};
        val = *(bf16x8*)tmp;
      } else {
        const __bf16* ib = (const __bf16*)inp + (size_t)b * BH * BW * CB;
        val = *(const bf16x8*)(ib + ((size_t)gy * BW + gx) * CB + ch * 8);
      }
    } else {
      __bf16 tmp[8] = {(__bf16)0.f, (__bf16)0.f, (__bf16)0.f, (__bf16)0.f,
                       (__bf16)0.f, (__bf16)0.f, (__bf16)0.f, (__bf16)0.f};
      val = *(bf16x8*)tmp;
    }
    int byte = (q * 256 + ch * 16) ^ ((q & 7) << 4);
    *(bf16x8*)(ldsA + byte) = val;
  }
  __syncthreads();

  f32x4 acc[2][4];
#pragma unroll
  for (int i = 0; i < 2; ++i)
#pragma unroll
    for (int j = 0; j < 4; ++j) acc[i][j] = {0.f, 0.f, 0.f, 0.f};

  const int lrow = l & 15;
  const int kgrp = l >> 4;

  for (int tap = 0; tap < 9; ++tap) {
    if (tap) __syncthreads();
    {
      const __bf16* wp = wt + (size_t)tap * CB * CB;
      for (int i = threadIdx.x; i < 2048; i += 256) {
        int co = i >> 4;
        int ch = i & 15;
        uint4 val = *(const uint4*)(wp + co * CB + ch * 8);
        int byte = (co * 256 + ch * 16) ^ ((co & 7) << 4);
        *(uint4*)(ldsB + byte) = val;
      }
    }
    __syncthreads();

    const int ky = tap / 3, kx = tap % 3;
#pragma unroll
    for (int ks = 0; ks < 4; ++ks) {
      const int ci0b = (ks * 32 + kgrp * 8) * 2;
      bf16x8 afr[2], bfr[4];
#pragma unroll
      for (int fm = 0; fm < 2; ++fm) {
        int mpx = wm * 32 + fm * 16 + lrow;
        int q = (mpx / 8 + ky) * 10 + (mpx % 8 + kx);
        int byte = (q * 256 + ci0b) ^ ((q & 7) << 4);
        afr[fm] = *(const bf16x8*)(ldsA + byte);
      }
#pragma unroll
      for (int fn = 0; fn < 4; ++fn) {
        int r = wn * 64 + fn * 16 + lrow;
        int byte = (r * 256 + ci0b) ^ ((r & 7) << 4);
        bfr[fn] = *(const bf16x8*)(ldsB + byte);
      }
#pragma unroll
      for (int fm = 0; fm < 2; ++fm)
#pragma unroll
        for (int fn = 0; fn < 4; ++fn)
          acc[fm][fn] = __builtin_amdgcn_mfma_f32_16x16x32_bf16(
              afr[fm], bfr[fn], acc[fm][fn], 0, 0, 0);
    }
  }

  if (OUT_NCHW == 0) {
    __bf16* out = (__bf16*)outp;
#pragma unroll
    for (int fn = 0; fn < 4; ++fn) {
      int co = wn * 64 + fn * 16 + lrow;
      float sc = g[co] / sqrtf(v[co] + BEPS);
      float sh = be[co] - m[co] * sc + bias[co] * sc;
#pragma unroll
      for (int fm = 0; fm < 2; ++fm) {
#pragma unroll
        for (int r = 0; r < 4; ++r) {
          int mpx = wm * 32 + fm * 16 + kgrp * 4 + r;
          int y = y0 + mpx / 8, x = x0 + mpx % 8;
          float val = gelu_exact(acc[fm][fn][r] * sc + sh);
          out[((size_t)(b * BH + y) * BW + x) * CB + co] = (__bf16)val;
        }
      }
    }
  } else {
    __syncthreads();
    float* lo = (float*)ldsB;
#pragma unroll
    for (int fn = 0; fn < 4; ++fn) {
      int co = wn * 64 + fn * 16 + lrow;
      float sc = g[co] / sqrtf(v[co] + BEPS);
      float sh = be[co] - m[co] * sc + bias[co] * sc;
#pragma unroll
      for (int fm = 0; fm < 2; ++fm) {
#pragma unroll
        for (int r = 0; r < 4; ++r) {
          int mpx = wm * 32 + fm * 16 + kgrp * 4 + r;
          lo[mpx * 130 + co] = gelu_exact(acc[fm][fn][r] * sc + sh);
        }
      }
    }
    __syncthreads();
    float* out = (float*)outp;
    for (int pair = threadIdx.x; pair < 1024; pair += 256) {
      int co = pair >> 3, py = pair & 7;
      float tmp[8];
#pragma unroll
      for (int i = 0; i < 8; ++i) tmp[i] = lo[(py * 8 + i) * 130 + co];
      float* op = out + (((size_t)(b * CB + co) * BH) + (y0 + py)) * BW + x0;
      *(float4*)op = *(float4*)tmp;
      *(float4*)(op + 4) = *(float4*)(tmp + 4);
    }
  }
}

extern "C" void kernel_launch(void* const* d_in, const int* in_sizes, int n_in,
                              void* d_out, int out_size, void* d_ws, size_t ws_size,
                              hipStream_t stream) {
  const float* feat = (const float*)d_in[0];
  const float* Kmat = (const float*)d_in[1];
  const float* Tmat = (const float*)d_in[2];
  const float* trust = (const float*)d_in[3];
  const float* dh_w1 = (const float*)d_in[4];
  const float* dh_b1 = (const float*)d_in[5];
  const float* dh_g = (const float*)d_in[6];
  const float* dh_be = (const float*)d_in[7];
  const float* dh_m = (const float*)d_in[8];
  const float* dh_v = (const float*)d_in[9];
  const float* dh_w2 = (const float*)d_in[10];
  const float* dh_b2 = (const float*)d_in[11];
  const float* fp_w = (const float*)d_in[12];
  const float* fp_b = (const float*)d_in[13];
  const float* fp_g = (const float*)d_in[14];
  const float* fp_be = (const float*)d_in[15];
  const float* fp_m = (const float*)d_in[16];
  const float* fp_v = (const float*)d_in[17];
  const float* br_w1 = (const float*)d_in[18];
  const float* br_b1 = (const float*)d_in[19];
  const float* br_g1 = (const float*)d_in[20];
  const float* br_be1 = (const float*)d_in[21];
  const float* br_m1 = (const float*)d_in[22];
  const float* br_v1 = (const float*)d_in[23];
  const float* br_w2 = (const float*)d_in[24];
  const float* br_b2 = (const float*)d_in[25];
  const float* br_g2 = (const float*)d_in[26];
  const float* br_be2 = (const float*)d_in[27];
  const float* br_m2 = (const float*)d_in[28];
  const float* br_v2 = (const float*)d_in[29];

  float* ws = (float*)d_ws;
  float* dp_t = ws;                               // 537,600 f
  __bf16* fpnb = (__bf16*)(ws + 537600);          // 2,150,400 bf16 (1,075,200 f)
  float* bev = ws + 537600 + 1075200;             // 4,194,304 f
  float* after = bev + 4194304;
  __bf16* h1bf = (__bf16*)after;                         // 4,194,304 bf16
  __bf16* w1dh = (__bf16*)(after + 2097152);             // 36,864 bf16
  __bf16* w1bev = (__bf16*)(after + 2097152 + 18432);    // 147,456 bf16
  __bf16* w2bev = (__bf16*)(after + 2097152 + 18432 + 73728);
  __bf16* featT = (__bf16*)(after + 2097152 + 18432 + 2 * 73728);  // 1,075,200 bf16
  __bf16* hbuf = featT + 1075200;                        // 1,075,200 bf16

  // prep: transpose + all weight preps (1 dispatch)
  k_prep<<<264 + 1296, 256, 0, stream>>>(feat, dh_w1, br_w1, br_w2, featT,
                                         w1dh, w1bev, w2bev);
  // zero BEV accumulator
  hipMemsetAsync(bev, 0, (size_t)2 * BH * BW * CB * sizeof(float), stream);
  // depth-head conv (336 blocks)
  k_dh<<<N_IMG * HFEAT, 256, 0, stream>>>(featT, w1dh, dh_b1, dh_g, dh_be,
                                          dh_m, dh_v, hbuf);
  // logits + softmax + feature projection (132 blocks)
  k_mid<<<N_IMG * 11, 256, 0, stream>>>(hbuf, featT, dh_w2, dh_b2, fp_w, fp_b,
                                        fp_g, fp_be, fp_m, fp_v, trust, dp_t,
                                        fpnb);
  // ray-factored scatter
  k_rayscatter<<<N_IMG * WFEAT, 256, 0, stream>>>(fpnb, dp_t, Kmat, Tmat, bev);
  // BEV refinement convs via MFMA
  k_bev_conv_mfma<1, 0><<<2 * 16 * 16, 256, 0, stream>>>(
      (const void*)bev, w1bev, br_b1, br_g1, br_be1, br_m1, br_v1, (void*)h1bf);
  k_bev_conv_mfma<0, 1><<<2 * 16 * 16, 256, 0, stream>>>(
      (const void*)h1bf, w2bev, br_b2, br_g2, br_be2, br_m2, br_v2, d_out);
}

// Round 8
// 168.202 us; speedup vs baseline: 1.1095x; 1.1009x over previous
//
#include <hip/hip_runtime.h>
#include <math.h>

#define N_IMG 12
#define C_IN 64
#define HFEAT 28
#define WFEAT 50
#define P_PIX 1400
#define ND 32
#define CB 128
#define BH 128
#define BW 128
#define BEPS 1e-5f

typedef float f32x4 __attribute__((ext_vector_type(4)));
typedef __bf16 bf16x8 __attribute__((ext_vector_type(8)));

__device__ __forceinline__ float gelu_exact(float x) {
  return 0.5f * x * (1.0f + erff(x * 0.70710678118654752440f));
}

// ---------------- prep: transpose + weight preps + bev zero, one kernel ------
// blocks [0,264): feat NCHW f32 -> NHWC bf16
// blocks [264,1560): weight preps
// blocks [1560,5656): zero bev (16 MB)
__global__ __launch_bounds__(256) void k_prep(
    const float* __restrict__ feat, const float* __restrict__ dh_w1,
    const float* __restrict__ br_w1, const float* __restrict__ br_w2,
    __bf16* __restrict__ featT, __bf16* __restrict__ w1dh,
    __bf16* __restrict__ w1bev, __bf16* __restrict__ w2bev,
    float* __restrict__ bev) {
  if (blockIdx.x < 264) {
    __shared__ float t[64][65];
    const int n = blockIdx.x / 22;
    const int p0 = (blockIdx.x % 22) * 64;
    const float* fb = feat + (size_t)n * C_IN * P_PIX;
    const int lane = threadIdx.x & 63;
    const int grp = threadIdx.x >> 6;
#pragma unroll
    for (int j = 0; j < 16; ++j) {
      int ci = j * 4 + grp;
      int px = p0 + lane;
      t[ci][lane] = (px < P_PIX) ? fb[ci * P_PIX + px] : 0.f;
    }
    __syncthreads();
#pragma unroll
    for (int k = 0; k < 2; ++k) {
      int gid = threadIdx.x * 2 + k;
      int pxl = gid >> 3, g = gid & 7;
      int px = p0 + pxl;
      if (px < P_PIX) {
        __bf16 tmp[8];
#pragma unroll
        for (int j = 0; j < 8; ++j) tmp[j] = (__bf16)t[g * 8 + j][pxl];
        *(bf16x8*)(featT + ((size_t)n * P_PIX + px) * C_IN + g * 8) = *(bf16x8*)tmp;
      }
    }
  } else if (blockIdx.x < 1560) {
    int idx = (blockIdx.x - 264) * 256 + threadIdx.x;
    if (idx < 9 * 64 * 64) {
      int ci = idx & 63, co = (idx >> 6) & 63, tap = idx >> 12;
      w1dh[idx] = (__bf16)dh_w1[(co * 64 + ci) * 9 + tap];
    } else if (idx < 9 * 64 * 64 + 9 * CB * CB) {
      int k = idx - 9 * 64 * 64;
      int ci = k % CB, co = (k / CB) % CB, tap = k / (CB * CB);
      w1bev[k] = (__bf16)br_w1[((size_t)co * CB + ci) * 9 + tap];
    } else if (idx < 9 * 64 * 64 + 2 * 9 * CB * CB) {
      int k = idx - 9 * 64 * 64 - 9 * CB * CB;
      int ci = k % CB, co = (k / CB) % CB, tap = k / (CB * CB);
      w2bev[k] = (__bf16)br_w2[((size_t)co * CB + ci) * 9 + tap];
    }
  } else {
    size_t off = ((size_t)(blockIdx.x - 1560) * 256 + threadIdx.x) * 4;
    *(float4*)(bev + off) = make_float4(0.f, 0.f, 0.f, 0.f);
  }
}

// ---------------- mega front: dh conv + logits + softmax + fp conv + G + atomics
// one block per (image, column). 600 blocks, 2 blocks/CU.
// LDS map (bytes):
#define FA_O 0        // featT stage [3 cols][32 rows][64 ci] bf16   12288
#define WD_O 12288    // W1 tap double-buffer 2 x [64co][64ci] bf16  16384
#define WF_O 28672    // Wfp [128co][64ci] bf16                      16384
#define W2_O 45056    // W2 [32d][64ci] bf16                          4096
#define HL_O 49152    // h [32px][64co] bf16 swizzled                 4096
#define FL_O 53248    // F [32px][132] f32                           16896
#define DP_O 70144    // logits/probs [32px][33] f32                  4224
#define GEO_O 74368   // vL[32], colL[32], rowL[32] int                384
#define LDS_TOT 74752

__global__ __launch_bounds__(256, 2) void k_mega(
    const __bf16* __restrict__ featT, const __bf16* __restrict__ w1bf,
    const float* __restrict__ dh_b1, const float* __restrict__ dh_g,
    const float* __restrict__ dh_be, const float* __restrict__ dh_m,
    const float* __restrict__ dh_v, const float* __restrict__ dh_w2,
    const float* __restrict__ dh_b2, const float* __restrict__ fp_w,
    const float* __restrict__ fp_b, const float* __restrict__ fp_g,
    const float* __restrict__ fp_be, const float* __restrict__ fp_m,
    const float* __restrict__ fp_v, const float* __restrict__ trust,
    const float* __restrict__ Kmat, const float* __restrict__ Tmat,
    float* __restrict__ bev) {
  __shared__ __align__(16) unsigned char lds[LDS_TOT];
  const int n = blockIdx.x / WFEAT;
  const int xc = blockIdx.x % WFEAT;
  const int tid = threadIdx.x;
  const int l = tid & 63;
  const int wid = tid >> 6;
  const int lrow = l & 15;
  const int kgrp = l >> 4;
  int* vL = (int*)(lds + GEO_O);
  int* colL = vL + 32;
  int* rowL = colL + 32;

  // ---- geometry per depth (bitwise identical to previous rayscatter) ----
  if (tid < 32) {
    int d = tid;
    const float* Kp = Kmat + n * 9;
    float fx = Kp[0], cx = Kp[2];
    float rx = ((float)xc - cx) / fx;
    const float* Tp = Tmat + n * 16;
    float depth = 1.0f + (float)d * (49.0f / 31.0f);
    float pcx = rx * depth, pcz = depth;
    float Xx = Tp[0] * pcx + Tp[2] * pcz + Tp[3];
    float Xy = Tp[4] * pcx + Tp[6] * pcz + Tp[7];
    float uf = (Xx + 20.0f) / 40.0f * 127.0f;
    float vf = (Xy + 20.0f) / 40.0f * 127.0f;
    vL[d] = (uf > -1.0f && uf < 128.0f && vf > -1.0f && vf < 128.0f) ? 1 : 0;
    colL[d] = (int)uf;
    rowL[d] = (int)vf;
  }

  // ---- stage FA: 3 cols x 32 rows x 64ci ----
  {
    const __bf16* fT = featT + (size_t)n * P_PIX * C_IN;
    for (int i2 = tid; i2 < 768; i2 += 256) {
      int q = i2 >> 3, g = i2 & 7;
      int kx = q >> 5, i = q & 31;
      int r = i - 1, col = xc - 1 + kx;
      bf16x8 val;
      if (r >= 0 && r < HFEAT && col >= 0 && col < WFEAT) {
        val = *(const bf16x8*)(fT + ((size_t)(r * WFEAT + col)) * C_IN + g * 8);
      } else {
        __bf16 z[8] = {};
        val = *(bf16x8*)z;
      }
      *(bf16x8*)(lds + FA_O + q * 128 + ((g ^ (q & 7)) << 4)) = val;
    }
  }
  // ---- stage W1 tap 0 ----
  for (int i2 = tid; i2 < 512; i2 += 256) {
    int co = i2 >> 3, g = i2 & 7;
    uint4 v = *(const uint4*)(w1bf + co * 64 + g * 8);
    *(uint4*)(lds + WD_O + co * 128 + ((g ^ (co & 7)) << 4)) = v;
  }
  // ---- stage Wfp (fp32 -> bf16) ----
  for (int i2 = tid; i2 < 1024; i2 += 256) {
    int co = i2 >> 3, g = i2 & 7;
    const float* sp = fp_w + co * 64 + g * 8;
    __bf16 t8[8];
#pragma unroll
    for (int j = 0; j < 8; ++j) t8[j] = (__bf16)sp[j];
    *(bf16x8*)(lds + WF_O + co * 128 + ((g ^ (co & 7)) << 4)) = *(bf16x8*)t8;
  }
  // ---- stage W2 ----
  {
    int d = tid >> 3, g = tid & 7;
    const float* sp = dh_w2 + d * 64 + g * 8;
    __bf16 t8[8];
#pragma unroll
    for (int j = 0; j < 8; ++j) t8[j] = (__bf16)sp[j];
    *(bf16x8*)(lds + W2_O + d * 128 + ((g ^ (d & 7)) << 4)) = *(bf16x8*)t8;
  }
  __syncthreads();

  // ---- dh 3x3 conv MFMA: M=32px(28) N=64co(16/wave) K=576, tap-dbuf ----
  f32x4 acc_h[2];
  acc_h[0] = {0.f, 0.f, 0.f, 0.f};
  acc_h[1] = {0.f, 0.f, 0.f, 0.f};
  const int co_h = wid * 16 + lrow;
  for (int tap = 0; tap < 9; ++tap) {
    if (tap < 8) {
      const __bf16* wp = w1bf + (size_t)(tap + 1) * 4096;
      unsigned char* wb = lds + WD_O + ((tap + 1) & 1) * 8192;
      for (int i2 = tid; i2 < 512; i2 += 256) {
        int co = i2 >> 3, g = i2 & 7;
        uint4 v = *(const uint4*)(wp + co * 64 + g * 8);
        *(uint4*)(wb + co * 128 + ((g ^ (co & 7)) << 4)) = v;
      }
    }
    const int ky = tap / 3, kx = tap % 3;
    const unsigned char* wb = lds + WD_O + (tap & 1) * 8192;
#pragma unroll
    for (int ks = 0; ks < 2; ++ks) {
      const int gran = ks * 4 + kgrp;
      bf16x8 afr[2];
#pragma unroll
      for (int fm = 0; fm < 2; ++fm) {
        int pxr = fm * 16 + lrow;
        if (pxr > 27) pxr = 27;
        int q = kx * 32 + pxr + ky;
        afr[fm] = *(const bf16x8*)(lds + FA_O + q * 128 + ((gran ^ (q & 7)) << 4));
      }
      bf16x8 bfr = *(const bf16x8*)(wb + co_h * 128 + ((gran ^ (co_h & 7)) << 4));
#pragma unroll
      for (int fm = 0; fm < 2; ++fm)
        acc_h[fm] = __builtin_amdgcn_mfma_f32_16x16x32_bf16(afr[fm], bfr,
                                                            acc_h[fm], 0, 0, 0);
    }
    __syncthreads();
  }

  // ---- fp 1x1 conv MFMA: M=32px N=128co(32/wave) K=64 (reads FA center) ----
  f32x4 acc_fp[2][2];
#pragma unroll
  for (int i = 0; i < 2; ++i)
#pragma unroll
    for (int j = 0; j < 2; ++j) acc_fp[i][j] = {0.f, 0.f, 0.f, 0.f};
#pragma unroll
  for (int ks = 0; ks < 2; ++ks) {
    const int gran = ks * 4 + kgrp;
    bf16x8 afr[2];
#pragma unroll
    for (int fm = 0; fm < 2; ++fm) {
      int pxr = fm * 16 + lrow;
      if (pxr > 27) pxr = 27;
      int q = 32 + pxr + 1;  // center col plane kx=1, row offset +1
      afr[fm] = *(const bf16x8*)(lds + FA_O + q * 128 + ((gran ^ (q & 7)) << 4));
    }
    bf16x8 bfr[2];
#pragma unroll
    for (int fn = 0; fn < 2; ++fn) {
      int co = wid * 32 + fn * 16 + lrow;
      bfr[fn] = *(const bf16x8*)(lds + WF_O + co * 128 + ((gran ^ (co & 7)) << 4));
    }
#pragma unroll
    for (int fm = 0; fm < 2; ++fm)
#pragma unroll
      for (int fn = 0; fn < 2; ++fn)
        acc_fp[fm][fn] = __builtin_amdgcn_mfma_f32_16x16x32_bf16(
            afr[fm], bfr[fn], acc_fp[fm][fn], 0, 0, 0);
  }

  // ---- h epilogue: BN + GELU -> HL bf16 (swizzled) ----
  {
    float sc = dh_g[co_h] / sqrtf(dh_v[co_h] + BEPS);
    float sh = dh_be[co_h] - dh_m[co_h] * sc + dh_b1[co_h] * sc;
#pragma unroll
    for (int fm = 0; fm < 2; ++fm) {
#pragma unroll
      for (int rr = 0; rr < 4; ++rr) {
        int px = fm * 16 + kgrp * 4 + rr;
        float val = gelu_exact(acc_h[fm][rr] * sc + sh);
        *(__bf16*)(lds + HL_O + px * 128 + (((co_h >> 3) ^ (px & 7)) << 4) +
                   (co_h & 7) * 2) = (__bf16)val;
      }
    }
  }
  // ---- fp epilogue: BN + GELU -> FL f32 ----
  {
    float* FLf = (float*)(lds + FL_O);
#pragma unroll
    for (int fn = 0; fn < 2; ++fn) {
      int co = wid * 32 + fn * 16 + lrow;
      float sc = fp_g[co] / sqrtf(fp_v[co] + BEPS);
      float sh = fp_be[co] - fp_m[co] * sc + fp_b[co] * sc;
#pragma unroll
      for (int fm = 0; fm < 2; ++fm) {
#pragma unroll
        for (int rr = 0; rr < 4; ++rr) {
          int px = fm * 16 + kgrp * 4 + rr;
          FLf[px * 132 + co] = gelu_exact(acc_fp[fm][fn][rr] * sc + sh);
        }
      }
    }
  }
  __syncthreads();

  // ---- depth logits MFMA: M=32px N=32d K=64 (waves 0,1) -> DP ----
  if (wid < 2) {
    f32x4 acc_l[2];
    acc_l[0] = {0.f, 0.f, 0.f, 0.f};
    acc_l[1] = {0.f, 0.f, 0.f, 0.f};
    const int dcol = wid * 16 + lrow;
#pragma unroll
    for (int ks = 0; ks < 2; ++ks) {
      const int gran = ks * 4 + kgrp;
      bf16x8 afr[2];
#pragma unroll
      for (int fm = 0; fm < 2; ++fm) {
        int px = fm * 16 + lrow;
        afr[fm] = *(const bf16x8*)(lds + HL_O + px * 128 + ((gran ^ (px & 7)) << 4));
      }
      bf16x8 bfr = *(const bf16x8*)(lds + W2_O + dcol * 128 + ((gran ^ (dcol & 7)) << 4));
#pragma unroll
      for (int fm = 0; fm < 2; ++fm)
        acc_l[fm] = __builtin_amdgcn_mfma_f32_16x16x32_bf16(afr[fm], bfr,
                                                            acc_l[fm], 0, 0, 0);
    }
    float b2v = dh_b2[dcol];
    float* dp = (float*)(lds + DP_O);
#pragma unroll
    for (int fm = 0; fm < 2; ++fm) {
#pragma unroll
      for (int rr = 0; rr < 4; ++rr) {
        int px = fm * 16 + kgrp * 4 + rr;
        dp[px * 33 + dcol] = acc_l[fm][rr] + b2v;
      }
    }
  }
  __syncthreads();

  // ---- softmax (+trust fold) in place ----
  if (tid < 28) {
    float* dp = (float*)(lds + DP_O);
    float lg[ND];
#pragma unroll
    for (int d = 0; d < ND; ++d) lg[d] = dp[tid * 33 + d];
    float mx = lg[0];
#pragma unroll
    for (int d = 1; d < ND; ++d) mx = fmaxf(mx, lg[d]);
    float sum = 0.f;
#pragma unroll
    for (int d = 0; d < ND; ++d) {
      lg[d] = expf(lg[d] - mx);
      sum += lg[d];
    }
    float inv = trust[n] / sum;
#pragma unroll
    for (int d = 0; d < ND; ++d) dp[tid * 33 + d] = lg[d] * inv;
  }
  __syncthreads();

  // ---- G[d][c] = sum_r dp[r][d]*F[r][c]; direct coalesced atomics ----
  {
    const int d = tid >> 3, cg = tid & 7;
    if (vL[d]) {
      const float* dp = (const float*)(lds + DP_O);
      const float* FLf = (const float*)(lds + FL_O);
      float a[16];
#pragma unroll
      for (int j = 0; j < 16; ++j) a[j] = 0.f;
      for (int r = 0; r < 28; ++r) {
        float dv = dp[r * 33 + d];
        const float* fr = FLf + r * 132 + cg * 16;
#pragma unroll
        for (int j = 0; j < 16; ++j) a[j] = fmaf(dv, fr[j], a[j]);
      }
      const int b = n / 6;
      float* bb = bev + ((size_t)b * (BH * BW) + rowL[d] * BW + colL[d]) * CB +
                  cg * 16;
#pragma unroll
      for (int j = 0; j < 16; ++j) atomicAdd(bb + j, a[j]);
    }
  }
}

// ---------------- BEV 3x3 conv via bf16 MFMA (unchanged) ----------------
template <int IN_F32, int OUT_NCHW>
__global__ __launch_bounds__(256) void k_bev_conv_mfma(
    const void* __restrict__ inp, const __bf16* __restrict__ wt,
    const float* __restrict__ bias, const float* __restrict__ g,
    const float* __restrict__ be, const float* __restrict__ m,
    const float* __restrict__ v, void* __restrict__ outp) {
  __shared__ __align__(16) unsigned char ldsA[10 * 10 * CB * 2];
  __shared__ __align__(16) unsigned char ldsB[64 * 130 * 4];

  const int blk = blockIdx.x;
  const int tx = blk % 16;
  const int ty = (blk / 16) % 16;
  const int b = blk / 256;
  const int y0 = ty * 8, x0 = tx * 8;

  const int l = threadIdx.x & 63;
  const int wid = threadIdx.x >> 6;
  const int wm = wid & 1;
  const int wn = wid >> 1;

  for (int i = threadIdx.x; i < 1600; i += 256) {
    int q = i >> 4;
    int ch = i & 15;
    int hy = q / 10, hx = q % 10;
    int gy = y0 + hy - 1, gx = x0 + hx - 1;
    bf16x8 val;
    if (gy >= 0 && gy < BH && gx >= 0 && gx < BW) {
      if (IN_F32) {
        const float* ib = (const float*)inp + (size_t)b * BH * BW * CB;
        const float* sp = ib + ((size_t)gy * BW + gx) * CB + ch * 8;
        float4 a = *(const float4*)sp;
        float4 bb = *(const float4*)(sp + 4);
        __bf16 tmp[8] = {(__bf16)a.x,  (__bf16)a.y,  (__bf16)a.z,  (__bf16)a.w,
                         (__bf16)bb.x, (__bf16)bb.y, (__bf16)bb.z, (__bf16)bb.w};
        val = *(bf16x8*)tmp;
      } else {
        const __bf16* ib = (const __bf16*)inp + (size_t)b * BH * BW * CB;
        val = *(const bf16x8*)(ib + ((size_t)gy * BW + gx) * CB + ch * 8);
      }
    } else {
      __bf16 tmp[8] = {(__bf16)0.f, (__bf16)0.f, (__bf16)0.f, (__bf16)0.f,
                       (__bf16)0.f, (__bf16)0.f, (__bf16)0.f, (__bf16)0.f};
      val = *(bf16x8*)tmp;
    }
    int byte = (q * 256 + ch * 16) ^ ((q & 7) << 4);
    *(bf16x8*)(ldsA + byte) = val;
  }
  __syncthreads();

  f32x4 acc[2][4];
#pragma unroll
  for (int i = 0; i < 2; ++i)
#pragma unroll
    for (int j = 0; j < 4; ++j) acc[i][j] = {0.f, 0.f, 0.f, 0.f};

  const int lrow = l & 15;
  const int kgrp = l >> 4;

  for (int tap = 0; tap < 9; ++tap) {
    if (tap) __syncthreads();
    {
      const __bf16* wp = wt + (size_t)tap * CB * CB;
      for (int i = threadIdx.x; i < 2048; i += 256) {
        int co = i >> 4;
        int ch = i & 15;
        uint4 val = *(const uint4*)(wp + co * CB + ch * 8);
        int byte = (co * 256 + ch * 16) ^ ((co & 7) << 4);
        *(uint4*)(ldsB + byte) = val;
      }
    }
    __syncthreads();

    const int ky = tap / 3, kx = tap % 3;
#pragma unroll
    for (int ks = 0; ks < 4; ++ks) {
      const int ci0b = (ks * 32 + kgrp * 8) * 2;
      bf16x8 afr[2], bfr[4];
#pragma unroll
      for (int fm = 0; fm < 2; ++fm) {
        int mpx = wm * 32 + fm * 16 + lrow;
        int q = (mpx / 8 + ky) * 10 + (mpx % 8 + kx);
        int byte = (q * 256 + ci0b) ^ ((q & 7) << 4);
        afr[fm] = *(const bf16x8*)(ldsA + byte);
      }
#pragma unroll
      for (int fn = 0; fn < 4; ++fn) {
        int r = wn * 64 + fn * 16 + lrow;
        int byte = (r * 256 + ci0b) ^ ((r & 7) << 4);
        bfr[fn] = *(const bf16x8*)(ldsB + byte);
      }
#pragma unroll
      for (int fm = 0; fm < 2; ++fm)
#pragma unroll
        for (int fn = 0; fn < 4; ++fn)
          acc[fm][fn] = __builtin_amdgcn_mfma_f32_16x16x32_bf16(
              afr[fm], bfr[fn], acc[fm][fn], 0, 0, 0);
    }
  }

  if (OUT_NCHW == 0) {
    __bf16* out = (__bf16*)outp;
#pragma unroll
    for (int fn = 0; fn < 4; ++fn) {
      int co = wn * 64 + fn * 16 + lrow;
      float sc = g[co] / sqrtf(v[co] + BEPS);
      float sh = be[co] - m[co] * sc + bias[co] * sc;
#pragma unroll
      for (int fm = 0; fm < 2; ++fm) {
#pragma unroll
        for (int r = 0; r < 4; ++r) {
          int mpx = wm * 32 + fm * 16 + kgrp * 4 + r;
          int y = y0 + mpx / 8, x = x0 + mpx % 8;
          float val = gelu_exact(acc[fm][fn][r] * sc + sh);
          out[((size_t)(b * BH + y) * BW + x) * CB + co] = (__bf16)val;
        }
      }
    }
  } else {
    __syncthreads();
    float* lo = (float*)ldsB;
#pragma unroll
    for (int fn = 0; fn < 4; ++fn) {
      int co = wn * 64 + fn * 16 + lrow;
      float sc = g[co] / sqrtf(v[co] + BEPS);
      float sh = be[co] - m[co] * sc + bias[co] * sc;
#pragma unroll
      for (int fm = 0; fm < 2; ++fm) {
#pragma unroll
        for (int r = 0; r < 4; ++r) {
          int mpx = wm * 32 + fm * 16 + kgrp * 4 + r;
          lo[mpx * 130 + co] = gelu_exact(acc[fm][fn][r] * sc + sh);
        }
      }
    }
    __syncthreads();
    float* out = (float*)outp;
    for (int pair = threadIdx.x; pair < 1024; pair += 256) {
      int co = pair >> 3, py = pair & 7;
      float tmp[8];
#pragma unroll
      for (int i = 0; i < 8; ++i) tmp[i] = lo[(py * 8 + i) * 130 + co];
      float* op = out + (((size_t)(b * CB + co) * BH) + (y0 + py)) * BW + x0;
      *(float4*)op = *(float4*)tmp;
      *(float4*)(op + 4) = *(float4*)(tmp + 4);
    }
  }
}

extern "C" void kernel_launch(void* const* d_in, const int* in_sizes, int n_in,
                              void* d_out, int out_size, void* d_ws, size_t ws_size,
                              hipStream_t stream) {
  const float* feat = (const float*)d_in[0];
  const float* Kmat = (const float*)d_in[1];
  const float* Tmat = (const float*)d_in[2];
  const float* trust = (const float*)d_in[3];
  const float* dh_w1 = (const float*)d_in[4];
  const float* dh_b1 = (const float*)d_in[5];
  const float* dh_g = (const float*)d_in[6];
  const float* dh_be = (const float*)d_in[7];
  const float* dh_m = (const float*)d_in[8];
  const float* dh_v = (const float*)d_in[9];
  const float* dh_w2 = (const float*)d_in[10];
  const float* dh_b2 = (const float*)d_in[11];
  const float* fp_w = (const float*)d_in[12];
  const float* fp_b = (const float*)d_in[13];
  const float* fp_g = (const float*)d_in[14];
  const float* fp_be = (const float*)d_in[15];
  const float* fp_m = (const float*)d_in[16];
  const float* fp_v = (const float*)d_in[17];
  const float* br_w1 = (const float*)d_in[18];
  const float* br_b1 = (const float*)d_in[19];
  const float* br_g1 = (const float*)d_in[20];
  const float* br_be1 = (const float*)d_in[21];
  const float* br_m1 = (const float*)d_in[22];
  const float* br_v1 = (const float*)d_in[23];
  const float* br_w2 = (const float*)d_in[24];
  const float* br_b2 = (const float*)d_in[25];
  const float* br_g2 = (const float*)d_in[26];
  const float* br_be2 = (const float*)d_in[27];
  const float* br_m2 = (const float*)d_in[28];
  const float* br_v2 = (const float*)d_in[29];

  float* ws = (float*)d_ws;
  float* bev = ws;                                       // 4,194,304 f
  float* after = bev + 4194304;
  __bf16* h1bf = (__bf16*)after;                         // 4,194,304 bf16
  __bf16* w1dh = (__bf16*)(after + 2097152);             // 36,864 bf16
  __bf16* w1bev = (__bf16*)(after + 2097152 + 18432);    // 147,456 bf16
  __bf16* w2bev = (__bf16*)(after + 2097152 + 18432 + 73728);
  __bf16* featT = (__bf16*)(after + 2097152 + 18432 + 2 * 73728);  // 1,075,200 bf16

  // prep: transpose + weight preps + bev zero (1 dispatch)
  k_prep<<<5656, 256, 0, stream>>>(feat, dh_w1, br_w1, br_w2, featT, w1dh,
                                   w1bev, w2bev, bev);
  // fused front: dh conv + logits + softmax + fp conv + ray G + atomics
  k_mega<<<N_IMG * WFEAT, 256, 0, stream>>>(
      featT, w1dh, dh_b1, dh_g, dh_be, dh_m, dh_v, dh_w2, dh_b2, fp_w, fp_b,
      fp_g, fp_be, fp_m, fp_v, trust, Kmat, Tmat, bev);
  // BEV refinement convs via MFMA
  k_bev_conv_mfma<1, 0><<<2 * 16 * 16, 256, 0, stream>>>(
      (const void*)bev, w1bev, br_b1, br_g1, br_be1, br_m1, br_v1, (void*)h1bf);
  k_bev_conv_mfma<0, 1><<<2 * 16 * 16, 256, 0, stream>>>(
      (const void*)h1bf, w2bev, br_b2, br_g2, br_be2, br_m2, br_v2, d_out);
}

// Round 9
// 99.803 us; speedup vs baseline: 1.8698x; 1.6853x over previous
//
#include <hip/hip_runtime.h>
#include <math.h>

#define N_IMG 12
#define C_IN 64
#define HFEAT 28
#define WFEAT 50
#define P_PIX 1400
#define ND 32
#define CB 128
#define BH 128
#define BW 128
#define BEPS 1e-5f

typedef float f32x4 __attribute__((ext_vector_type(4)));
typedef __bf16 bf16x8 __attribute__((ext_vector_type(8)));

__device__ __forceinline__ float gelu_exact(float x) {
  return 0.5f * x * (1.0f + erff(x * 0.70710678118654752440f));
}

// ---------------- prep: transpose + weight preps + bev zero, one kernel ------
// blocks [0,264): feat NCHW f32 -> NHWC bf16
// blocks [264,1600): weight preps (w1dh, w1bev, w2bev, wfpbf, w2bf)
// blocks [1600,5696): zero bev (16 MB)
__global__ __launch_bounds__(256) void k_prep(
    const float* __restrict__ feat, const float* __restrict__ dh_w1,
    const float* __restrict__ br_w1, const float* __restrict__ br_w2,
    const float* __restrict__ fp_w, const float* __restrict__ dh_w2,
    __bf16* __restrict__ featT, __bf16* __restrict__ w1dh,
    __bf16* __restrict__ w1bev, __bf16* __restrict__ w2bev,
    __bf16* __restrict__ wfpbf, __bf16* __restrict__ w2bf,
    float* __restrict__ bev) {
  if (blockIdx.x < 264) {
    __shared__ float t[64][65];
    const int n = blockIdx.x / 22;
    const int p0 = (blockIdx.x % 22) * 64;
    const float* fb = feat + (size_t)n * C_IN * P_PIX;
    const int lane = threadIdx.x & 63;
    const int grp = threadIdx.x >> 6;
#pragma unroll
    for (int j = 0; j < 16; ++j) {
      int ci = j * 4 + grp;
      int px = p0 + lane;
      t[ci][lane] = (px < P_PIX) ? fb[ci * P_PIX + px] : 0.f;
    }
    __syncthreads();
#pragma unroll
    for (int k = 0; k < 2; ++k) {
      int gid = threadIdx.x * 2 + k;
      int pxl = gid >> 3, g = gid & 7;
      int px = p0 + pxl;
      if (px < P_PIX) {
        __bf16 tmp[8];
#pragma unroll
        for (int j = 0; j < 8; ++j) tmp[j] = (__bf16)t[g * 8 + j][pxl];
        *(bf16x8*)(featT + ((size_t)n * P_PIX + px) * C_IN + g * 8) = *(bf16x8*)tmp;
      }
    }
  } else if (blockIdx.x < 1600) {
    int idx = (blockIdx.x - 264) * 256 + threadIdx.x;
    if (idx < 36864) {
      int ci = idx & 63, co = (idx >> 6) & 63, tap = idx >> 12;
      w1dh[idx] = (__bf16)dh_w1[(co * 64 + ci) * 9 + tap];
    } else if (idx < 36864 + 147456) {
      int k = idx - 36864;
      int ci = k % CB, co = (k / CB) % CB, tap = k / (CB * CB);
      w1bev[k] = (__bf16)br_w1[((size_t)co * CB + ci) * 9 + tap];
    } else if (idx < 36864 + 2 * 147456) {
      int k = idx - 36864 - 147456;
      int ci = k % CB, co = (k / CB) % CB, tap = k / (CB * CB);
      w2bev[k] = (__bf16)br_w2[((size_t)co * CB + ci) * 9 + tap];
    } else if (idx < 36864 + 2 * 147456 + 8192) {
      int k = idx - 36864 - 2 * 147456;
      wfpbf[k] = (__bf16)fp_w[k];  // [co][ci] layout preserved
    } else if (idx < 36864 + 2 * 147456 + 8192 + 2048) {
      int k = idx - 36864 - 2 * 147456 - 8192;
      w2bf[k] = (__bf16)dh_w2[k];  // [d][ci] layout preserved
    }
  } else {
    size_t off = ((size_t)(blockIdx.x - 1600) * 256 + threadIdx.x) * 4;
    *(float4*)(bev + off) = make_float4(0.f, 0.f, 0.f, 0.f);
  }
}

// ---------------- mega front v2: weights direct-from-L2, 3 blocks/CU --------
// one block per (image, column). 600 blocks, 54.3 KB LDS.
#define FA_O 0                      // [3 cols][32 rows][64 ci] bf16, 12288
#define HL_O 12288                  // h [32px][64co] bf16 swizzled,   4096
#define FL_O 16384                  // F [32px][132] f32,             16896
#define DP_O 33280                  // logits/probs [28(32)][33] f32,  4224
#define GEO_O (DP_O + 3696)         // vL[32] colL[32] rowL[32] in DP slack
#define G_O 37504                   // G [32][131] f32,               16768
#define LDS_TOT 54272

__global__ __launch_bounds__(256, 3) void k_mega(
    const __bf16* __restrict__ featT, const __bf16* __restrict__ w1bf,
    const float* __restrict__ dh_b1, const float* __restrict__ dh_g,
    const float* __restrict__ dh_be, const float* __restrict__ dh_m,
    const float* __restrict__ dh_v, const __bf16* __restrict__ w2bf,
    const float* __restrict__ dh_b2, const __bf16* __restrict__ wfpbf,
    const float* __restrict__ fp_b, const float* __restrict__ fp_g,
    const float* __restrict__ fp_be, const float* __restrict__ fp_m,
    const float* __restrict__ fp_v, const float* __restrict__ trust,
    const float* __restrict__ Kmat, const float* __restrict__ Tmat,
    float* __restrict__ bev) {
  __shared__ __align__(16) unsigned char lds[LDS_TOT];
  const int n = blockIdx.x / WFEAT;
  const int xc = blockIdx.x % WFEAT;
  const int tid = threadIdx.x;
  const int l = tid & 63;
  const int wid = tid >> 6;
  const int lrow = l & 15;
  const int kgrp = l >> 4;
  int* vL = (int*)(lds + GEO_O);
  int* colL = vL + 32;
  int* rowL = colL + 32;

  // ---- geometry per depth (bit-identical to prior rounds) ----
  if (tid < 32) {
    int d = tid;
    const float* Kp = Kmat + n * 9;
    float fx = Kp[0], cx = Kp[2];
    float rx = ((float)xc - cx) / fx;
    const float* Tp = Tmat + n * 16;
    float depth = 1.0f + (float)d * (49.0f / 31.0f);
    float pcx = rx * depth, pcz = depth;
    float Xx = Tp[0] * pcx + Tp[2] * pcz + Tp[3];
    float Xy = Tp[4] * pcx + Tp[6] * pcz + Tp[7];
    float uf = (Xx + 20.0f) / 40.0f * 127.0f;
    float vf = (Xy + 20.0f) / 40.0f * 127.0f;
    vL[d] = (uf > -1.0f && uf < 128.0f && vf > -1.0f && vf < 128.0f) ? 1 : 0;
    colL[d] = (int)uf;
    rowL[d] = (int)vf;
  }

  // ---- stage FA: 3 cols x 32 rows x 64ci ----
  {
    const __bf16* fT = featT + (size_t)n * P_PIX * C_IN;
    for (int i2 = tid; i2 < 768; i2 += 256) {
      int q = i2 >> 3, g = i2 & 7;
      int kx = q >> 5, i = q & 31;
      int r = i - 1, col = xc - 1 + kx;
      bf16x8 val;
      if (r >= 0 && r < HFEAT && col >= 0 && col < WFEAT) {
        val = *(const bf16x8*)(fT + ((size_t)(r * WFEAT + col)) * C_IN + g * 8);
      } else {
        __bf16 z[8] = {};
        val = *(bf16x8*)z;
      }
      *(bf16x8*)(lds + FA_O + q * 128 + ((g ^ (q & 7)) << 4)) = val;
    }
  }
  __syncthreads();  // barrier 1: FA ready

  // ---- dh 3x3 conv MFMA: B-frags direct from global (L2) ----
  f32x4 acc_h[2];
  acc_h[0] = {0.f, 0.f, 0.f, 0.f};
  acc_h[1] = {0.f, 0.f, 0.f, 0.f};
  const int co_h = wid * 16 + lrow;
#pragma unroll
  for (int tap = 0; tap < 9; ++tap) {
    const int ky = tap / 3, kx = tap % 3;
#pragma unroll
    for (int ks = 0; ks < 2; ++ks) {
      const int gran = ks * 4 + kgrp;
      bf16x8 afr[2];
#pragma unroll
      for (int fm = 0; fm < 2; ++fm) {
        int pxr = fm * 16 + lrow;
        if (pxr > 27) pxr = 27;
        int q = kx * 32 + pxr + ky;
        afr[fm] = *(const bf16x8*)(lds + FA_O + q * 128 + ((gran ^ (q & 7)) << 4));
      }
      bf16x8 bfr = *(const bf16x8*)(w1bf + tap * 4096 + co_h * 64 + gran * 8);
#pragma unroll
      for (int fm = 0; fm < 2; ++fm)
        acc_h[fm] = __builtin_amdgcn_mfma_f32_16x16x32_bf16(afr[fm], bfr,
                                                            acc_h[fm], 0, 0, 0);
    }
  }

  // ---- fp 1x1 conv MFMA: B-frags direct from global ----
  f32x4 acc_fp[2][2];
#pragma unroll
  for (int i = 0; i < 2; ++i)
#pragma unroll
    for (int j = 0; j < 2; ++j) acc_fp[i][j] = {0.f, 0.f, 0.f, 0.f};
#pragma unroll
  for (int ks = 0; ks < 2; ++ks) {
    const int gran = ks * 4 + kgrp;
    bf16x8 afr[2];
#pragma unroll
    for (int fm = 0; fm < 2; ++fm) {
      int pxr = fm * 16 + lrow;
      if (pxr > 27) pxr = 27;
      int q = 32 + pxr + 1;  // center tap plane
      afr[fm] = *(const bf16x8*)(lds + FA_O + q * 128 + ((gran ^ (q & 7)) << 4));
    }
    bf16x8 bfr[2];
#pragma unroll
    for (int fn = 0; fn < 2; ++fn) {
      int co = wid * 32 + fn * 16 + lrow;
      bfr[fn] = *(const bf16x8*)(wfpbf + co * 64 + gran * 8);
    }
#pragma unroll
    for (int fm = 0; fm < 2; ++fm)
#pragma unroll
      for (int fn = 0; fn < 2; ++fn)
        acc_fp[fm][fn] = __builtin_amdgcn_mfma_f32_16x16x32_bf16(
            afr[fm], bfr[fn], acc_fp[fm][fn], 0, 0, 0);
  }

  // ---- h epilogue: BN + GELU -> HL bf16 (swizzled) ----
  {
    float sc = dh_g[co_h] / sqrtf(dh_v[co_h] + BEPS);
    float sh = dh_be[co_h] - dh_m[co_h] * sc + dh_b1[co_h] * sc;
#pragma unroll
    for (int fm = 0; fm < 2; ++fm) {
#pragma unroll
      for (int rr = 0; rr < 4; ++rr) {
        int px = fm * 16 + kgrp * 4 + rr;
        float val = gelu_exact(acc_h[fm][rr] * sc + sh);
        *(__bf16*)(lds + HL_O + px * 128 + (((co_h >> 3) ^ (px & 7)) << 4) +
                   (co_h & 7) * 2) = (__bf16)val;
      }
    }
  }
  // ---- fp epilogue: BN + GELU -> FL f32 ----
  {
    float* FLf = (float*)(lds + FL_O);
#pragma unroll
    for (int fn = 0; fn < 2; ++fn) {
      int co = wid * 32 + fn * 16 + lrow;
      float sc = fp_g[co] / sqrtf(fp_v[co] + BEPS);
      float sh = fp_be[co] - fp_m[co] * sc + fp_b[co] * sc;
#pragma unroll
      for (int fm = 0; fm < 2; ++fm) {
#pragma unroll
        for (int rr = 0; rr < 4; ++rr) {
          int px = fm * 16 + kgrp * 4 + rr;
          FLf[px * 132 + co] = gelu_exact(acc_fp[fm][fn][rr] * sc + sh);
        }
      }
    }
  }
  __syncthreads();  // barrier 2: HL, FL ready

  // ---- depth logits MFMA (waves 0,1): B-frags direct from global ----
  if (wid < 2) {
    f32x4 acc_l[2];
    acc_l[0] = {0.f, 0.f, 0.f, 0.f};
    acc_l[1] = {0.f, 0.f, 0.f, 0.f};
    const int dcol = wid * 16 + lrow;
#pragma unroll
    for (int ks = 0; ks < 2; ++ks) {
      const int gran = ks * 4 + kgrp;
      bf16x8 afr[2];
#pragma unroll
      for (int fm = 0; fm < 2; ++fm) {
        int px = fm * 16 + lrow;
        afr[fm] = *(const bf16x8*)(lds + HL_O + px * 128 + ((gran ^ (px & 7)) << 4));
      }
      bf16x8 bfr = *(const bf16x8*)(w2bf + dcol * 64 + gran * 8);
#pragma unroll
      for (int fm = 0; fm < 2; ++fm)
        acc_l[fm] = __builtin_amdgcn_mfma_f32_16x16x32_bf16(afr[fm], bfr,
                                                            acc_l[fm], 0, 0, 0);
    }
    float b2v = dh_b2[dcol];
    float* dp = (float*)(lds + DP_O);
#pragma unroll
    for (int fm = 0; fm < 2; ++fm) {
#pragma unroll
      for (int rr = 0; rr < 4; ++rr) {
        int px = fm * 16 + kgrp * 4 + rr;
        if (px < 28) dp[px * 33 + dcol] = acc_l[fm][rr] + b2v;
      }
    }
  }
  __syncthreads();  // barrier 3: logits ready

  // ---- softmax (+trust fold) in place ----
  if (tid < 28) {
    float* dp = (float*)(lds + DP_O);
    float lg[ND];
#pragma unroll
    for (int d = 0; d < ND; ++d) lg[d] = dp[tid * 33 + d];
    float mx = lg[0];
#pragma unroll
    for (int d = 1; d < ND; ++d) mx = fmaxf(mx, lg[d]);
    float sum = 0.f;
#pragma unroll
    for (int d = 0; d < ND; ++d) {
      lg[d] = expf(lg[d] - mx);
      sum += lg[d];
    }
    float inv = trust[n] / sum;
#pragma unroll
    for (int d = 0; d < ND; ++d) dp[tid * 33 + d] = lg[d] * inv;
  }
  __syncthreads();  // barrier 4: probs ready

  // ---- G[d][c] = sum_r dp[r][d]*F[r][c] -> G LDS (float4 FL reads) ----
  {
    const int d = tid >> 3, cg = tid & 7;
    if (vL[d]) {
      const float* dp = (const float*)(lds + DP_O);
      const float* FLf = (const float*)(lds + FL_O);
      float a[16];
#pragma unroll
      for (int j = 0; j < 16; ++j) a[j] = 0.f;
      for (int r = 0; r < 28; ++r) {
        float dv = dp[r * 33 + d];
        const float4* fr = (const float4*)(FLf + r * 132 + cg * 16);
        float4 f0 = fr[0], f1 = fr[1], f2 = fr[2], f3 = fr[3];
        a[0] = fmaf(dv, f0.x, a[0]);  a[1] = fmaf(dv, f0.y, a[1]);
        a[2] = fmaf(dv, f0.z, a[2]);  a[3] = fmaf(dv, f0.w, a[3]);
        a[4] = fmaf(dv, f1.x, a[4]);  a[5] = fmaf(dv, f1.y, a[5]);
        a[6] = fmaf(dv, f1.z, a[6]);  a[7] = fmaf(dv, f1.w, a[7]);
        a[8] = fmaf(dv, f2.x, a[8]);  a[9] = fmaf(dv, f2.y, a[9]);
        a[10] = fmaf(dv, f2.z, a[10]); a[11] = fmaf(dv, f2.w, a[11]);
        a[12] = fmaf(dv, f3.x, a[12]); a[13] = fmaf(dv, f3.y, a[13]);
        a[14] = fmaf(dv, f3.z, a[14]); a[15] = fmaf(dv, f3.w, a[15]);
      }
      float* gw = (float*)(lds + G_O) + d * 131 + cg * 16;
#pragma unroll
      for (int j = 0; j < 16; ++j) gw[j] = a[j];
    }
  }
  __syncthreads();  // barrier 5: G ready

  // ---- coalesced atomic phase: lanes = contiguous channels of one cell ----
  {
    const int hd = tid >> 7;
    const int c = tid & 127;
    const int b = n / 6;
    const float* Gf = (const float*)(lds + G_O);
    float* bb = bev + ((size_t)b * (BH * BW)) * CB + c;
    for (int d0 = 0; d0 < ND; d0 += 2) {
      int d = d0 + hd;
      if (vL[d])
        atomicAdd(bb + ((size_t)rowL[d] * BW + colL[d]) * CB, Gf[d * 131 + c]);
    }
  }
}

// ---------------- BEV 3x3 conv via bf16 MFMA (unchanged) ----------------
template <int IN_F32, int OUT_NCHW>
__global__ __launch_bounds__(256) void k_bev_conv_mfma(
    const void* __restrict__ inp, const __bf16* __restrict__ wt,
    const float* __restrict__ bias, const float* __restrict__ g,
    const float* __restrict__ be, const float* __restrict__ m,
    const float* __restrict__ v, void* __restrict__ outp) {
  __shared__ __align__(16) unsigned char ldsA[10 * 10 * CB * 2];
  __shared__ __align__(16) unsigned char ldsB[64 * 130 * 4];

  const int blk = blockIdx.x;
  const int tx = blk % 16;
  const int ty = (blk / 16) % 16;
  const int b = blk / 256;
  const int y0 = ty * 8, x0 = tx * 8;

  const int l = threadIdx.x & 63;
  const int wid = threadIdx.x >> 6;
  const int wm = wid & 1;
  const int wn = wid >> 1;

  for (int i = threadIdx.x; i < 1600; i += 256) {
    int q = i >> 4;
    int ch = i & 15;
    int hy = q / 10, hx = q % 10;
    int gy = y0 + hy - 1, gx = x0 + hx - 1;
    bf16x8 val;
    if (gy >= 0 && gy < BH && gx >= 0 && gx < BW) {
      if (IN_F32) {
        const float* ib = (const float*)inp + (size_t)b * BH * BW * CB;
        const float* sp = ib + ((size_t)gy * BW + gx) * CB + ch * 8;
        float4 a = *(const float4*)sp;
        float4 bb = *(const float4*)(sp + 4);
        __bf16 tmp[8] = {(__bf16)a.x,  (__bf16)a.y,  (__bf16)a.z,  (__bf16)a.w,
                         (__bf16)bb.x, (__bf16)bb.y, (__bf16)bb.z, (__bf16)bb.w};
        val = *(bf16x8*)tmp;
      } else {
        const __bf16* ib = (const __bf16*)inp + (size_t)b * BH * BW * CB;
        val = *(const bf16x8*)(ib + ((size_t)gy * BW + gx) * CB + ch * 8);
      }
    } else {
      __bf16 tmp[8] = {(__bf16)0.f, (__bf16)0.f, (__bf16)0.f, (__bf16)0.f,
                       (__bf16)0.f, (__bf16)0.f, (__bf16)0.f, (__bf16)0.f};
      val = *(bf16x8*)tmp;
    }
    int byte = (q * 256 + ch * 16) ^ ((q & 7) << 4);
    *(bf16x8*)(ldsA + byte) = val;
  }
  __syncthreads();

  f32x4 acc[2][4];
#pragma unroll
  for (int i = 0; i < 2; ++i)
#pragma unroll
    for (int j = 0; j < 4; ++j) acc[i][j] = {0.f, 0.f, 0.f, 0.f};

  const int lrow = l & 15;
  const int kgrp = l >> 4;

  for (int tap = 0; tap < 9; ++tap) {
    if (tap) __syncthreads();
    {
      const __bf16* wp = wt + (size_t)tap * CB * CB;
      for (int i = threadIdx.x; i < 2048; i += 256) {
        int co = i >> 4;
        int ch = i & 15;
        uint4 val = *(const uint4*)(wp + co * CB + ch * 8);
        int byte = (co * 256 + ch * 16) ^ ((co & 7) << 4);
        *(uint4*)(ldsB + byte) = val;
      }
    }
    __syncthreads();

    const int ky = tap / 3, kx = tap % 3;
#pragma unroll
    for (int ks = 0; ks < 4; ++ks) {
      const int ci0b = (ks * 32 + kgrp * 8) * 2;
      bf16x8 afr[2], bfr[4];
#pragma unroll
      for (int fm = 0; fm < 2; ++fm) {
        int mpx = wm * 32 + fm * 16 + lrow;
        int q = (mpx / 8 + ky) * 10 + (mpx % 8 + kx);
        int byte = (q * 256 + ci0b) ^ ((q & 7) << 4);
        afr[fm] = *(const bf16x8*)(ldsA + byte);
      }
#pragma unroll
      for (int fn = 0; fn < 4; ++fn) {
        int r = wn * 64 + fn * 16 + lrow;
        int byte = (r * 256 + ci0b) ^ ((r & 7) << 4);
        bfr[fn] = *(const bf16x8*)(ldsB + byte);
      }
#pragma unroll
      for (int fm = 0; fm < 2; ++fm)
#pragma unroll
        for (int fn = 0; fn < 4; ++fn)
          acc[fm][fn] = __builtin_amdgcn_mfma_f32_16x16x32_bf16(
              afr[fm], bfr[fn], acc[fm][fn], 0, 0, 0);
    }
  }

  if (OUT_NCHW == 0) {
    __bf16* out = (__bf16*)outp;
#pragma unroll
    for (int fn = 0; fn < 4; ++fn) {
      int co = wn * 64 + fn * 16 + lrow;
      float sc = g[co] / sqrtf(v[co] + BEPS);
      float sh = be[co] - m[co] * sc + bias[co] * sc;
#pragma unroll
      for (int fm = 0; fm < 2; ++fm) {
#pragma unroll
        for (int r = 0; r < 4; ++r) {
          int mpx = wm * 32 + fm * 16 + kgrp * 4 + r;
          int y = y0 + mpx / 8, x = x0 + mpx % 8;
          float val = gelu_exact(acc[fm][fn][r] * sc + sh);
          out[((size_t)(b * BH + y) * BW + x) * CB + co] = (__bf16)val;
        }
      }
    }
  } else {
    __syncthreads();
    float* lo = (float*)ldsB;
#pragma unroll
    for (int fn = 0; fn < 4; ++fn) {
      int co = wn * 64 + fn * 16 + lrow;
      float sc = g[co] / sqrtf(v[co] + BEPS);
      float sh = be[co] - m[co] * sc + bias[co] * sc;
#pragma unroll
      for (int fm = 0; fm < 2; ++fm) {
#pragma unroll
        for (int r = 0; r < 4; ++r) {
          int mpx = wm * 32 + fm * 16 + kgrp * 4 + r;
          lo[mpx * 130 + co] = gelu_exact(acc[fm][fn][r] * sc + sh);
        }
      }
    }
    __syncthreads();
    float* out = (float*)outp;
    for (int pair = threadIdx.x; pair < 1024; pair += 256) {
      int co = pair >> 3, py = pair & 7;
      float tmp[8];
#pragma unroll
      for (int i = 0; i < 8; ++i) tmp[i] = lo[(py * 8 + i) * 130 + co];
      float* op = out + (((size_t)(b * CB + co) * BH) + (y0 + py)) * BW + x0;
      *(float4*)op = *(float4*)tmp;
      *(float4*)(op + 4) = *(float4*)(tmp + 4);
    }
  }
}

extern "C" void kernel_launch(void* const* d_in, const int* in_sizes, int n_in,
                              void* d_out, int out_size, void* d_ws, size_t ws_size,
                              hipStream_t stream) {
  const float* feat = (const float*)d_in[0];
  const float* Kmat = (const float*)d_in[1];
  const float* Tmat = (const float*)d_in[2];
  const float* trust = (const float*)d_in[3];
  const float* dh_w1 = (const float*)d_in[4];
  const float* dh_b1 = (const float*)d_in[5];
  const float* dh_g = (const float*)d_in[6];
  const float* dh_be = (const float*)d_in[7];
  const float* dh_m = (const float*)d_in[8];
  const float* dh_v = (const float*)d_in[9];
  const float* dh_w2 = (const float*)d_in[10];
  const float* dh_b2 = (const float*)d_in[11];
  const float* fp_w = (const float*)d_in[12];
  const float* fp_b = (const float*)d_in[13];
  const float* fp_g = (const float*)d_in[14];
  const float* fp_be = (const float*)d_in[15];
  const float* fp_m = (const float*)d_in[16];
  const float* fp_v = (const float*)d_in[17];
  const float* br_w1 = (const float*)d_in[18];
  const float* br_b1 = (const float*)d_in[19];
  const float* br_g1 = (const float*)d_in[20];
  const float* br_be1 = (const float*)d_in[21];
  const float* br_m1 = (const float*)d_in[22];
  const float* br_v1 = (const float*)d_in[23];
  const float* br_w2 = (const float*)d_in[24];
  const float* br_b2 = (const float*)d_in[25];
  const float* br_g2 = (const float*)d_in[26];
  const float* br_be2 = (const float*)d_in[27];
  const float* br_m2 = (const float*)d_in[28];
  const float* br_v2 = (const float*)d_in[29];

  float* ws = (float*)d_ws;
  float* bev = ws;                                       // 4,194,304 f
  float* after = bev + 4194304;
  __bf16* h1bf = (__bf16*)after;                         // 4,194,304 bf16
  __bf16* w1dh = (__bf16*)(after + 2097152);             // 36,864 bf16
  __bf16* w1bev = (__bf16*)(after + 2097152 + 18432);    // 147,456 bf16
  __bf16* w2bev = (__bf16*)(after + 2097152 + 18432 + 73728);        // 147,456
  __bf16* wfpbf = (__bf16*)(after + 2097152 + 18432 + 2 * 73728);    // 8,192
  __bf16* w2bf = (__bf16*)(after + 2097152 + 18432 + 2 * 73728 + 4096);  // 2,048
  __bf16* featT = (__bf16*)(after + 2097152 + 18432 + 2 * 73728 + 4096 + 1024);

  // prep: transpose + weight preps + bev zero (1 dispatch)
  k_prep<<<5696, 256, 0, stream>>>(feat, dh_w1, br_w1, br_w2, fp_w, dh_w2,
                                   featT, w1dh, w1bev, w2bev, wfpbf, w2bf, bev);
  // fused front v2
  k_mega<<<N_IMG * WFEAT, 256, 0, stream>>>(
      featT, w1dh, dh_b1, dh_g, dh_be, dh_m, dh_v, w2bf, dh_b2, wfpbf, fp_b,
      fp_g, fp_be, fp_m, fp_v, trust, Kmat, Tmat, bev);
  // BEV refinement convs via MFMA
  k_bev_conv_mfma<1, 0><<<2 * 16 * 16, 256, 0, stream>>>(
      (const void*)bev, w1bev, br_b1, br_g1, br_be1, br_m1, br_v1, (void*)h1bf);
  k_bev_conv_mfma<0, 1><<<2 * 16 * 16, 256, 0, stream>>>(
      (const void*)h1bf, w2bev, br_b2, br_g2, br_be2, br_m2, br_v2, d_out);
}